// Round 2
// baseline (4493.462 us; speedup 1.0000x reference)
//
#include <hip/hip_runtime.h>
#include <hip/hip_bf16.h>

// Problem constants
constexpr int N_   = 20000;
constexpr int E_   = 320000;
constexpr int M_   = 3;
constexpr int KIN  = 128;   // in_size
constexpr int H_   = 4;     // heads
constexpr int D_   = 64;    // per-head dim
constexpr int HD_  = 256;   // H*D
constexpr int HID_ = 128;   // semantic hidden
#define NEG_SLOPE 0.2f

// Workspace layout (bytes)
constexpr size_t FEAT_OFF = 0;                    // ushort[M*N*HD]   = 30,720,000 B (internal bf16)
constexpr size_t Z_OFF    = 30720000;             // float [M*N*HD]   = 61,440,000 B
constexpr size_t EL_OFF   = 92160000;             // float [M*N*H]    =    960,000 B
constexpr size_t ER_OFF   = 93120000;             // float [M*N*H]    =    960,000 B
constexpr size_t EE_OFF   = 94080000;             // float [M*E*H]    = 15,360,000 B
constexpr size_t DEN_OFF  = 109440000;            // float [M*N*H]    =    960,000 B
constexpr size_t WSUM_OFF = 110400000;            // float [16]
constexpr size_t BETA_OFF = 110400064;            // float [16]
// total ~110.4 MB

__device__ __forceinline__ float bf2f(ushort u) {
    union { unsigned int i; float f; } v; v.i = ((unsigned int)u) << 16; return v.f;
}
__device__ __forceinline__ ushort f2bf(float f) {
    union { float f; unsigned int i; } v; v.f = f;
    unsigned int i = v.i;
    unsigned int r = (i + 0x7fffu + ((i >> 16) & 1u)) >> 16;   // RNE
    return (ushort)r;
}

// K0: z[m][n][c] = bias[m][c]
__global__ __launch_bounds__(256) void init_z(const float* __restrict__ bias,
                                              float* __restrict__ z) {
    int idx = blockIdx.x * 256 + threadIdx.x;          // float4 index over [M*N*HD/4]
    if (idx >= M_ * N_ * HD_ / 4) return;
    int c4 = idx & (HD_ / 4 - 1);                      // 64 float4 per row
    int mn = idx >> 6;                                 // m*N + n
    int m  = mn / N_;
    float4 b4 = *(const float4*)&bias[m * HD_ + 4 * c4];
    *(float4*)&z[(size_t)idx * 4] = b4;
}

// K1: feat = h @ W[m] (bf16 store, internal) + fused el/er epilogue.
// Block = 256 = 4 waves; wave -> one node; lane handles cols 4l..4l+3.
__global__ __launch_bounds__(256) void feat_gemm(
    const float* __restrict__ h, const float* __restrict__ W,
    const float* __restrict__ al, const float* __restrict__ ar,
    ushort* __restrict__ feat, float* __restrict__ el, float* __restrict__ er) {
    const int m    = blockIdx.y;
    const int wave = threadIdx.x >> 6;
    const int lane = threadIdx.x & 63;
    const int n    = blockIdx.x * 4 + wave;

    __shared__ float hs[4][KIN];
    {
        float2 p = *(const float2*)&h[(size_t)n * KIN + 2 * lane];
        hs[wave][2 * lane]     = p.x;
        hs[wave][2 * lane + 1] = p.y;
    }
    __syncthreads();

    const float* Wm = W + (size_t)m * KIN * HD_ + 4 * lane;
    float a0 = 0.f, a1 = 0.f, a2 = 0.f, a3 = 0.f;
#pragma unroll 8
    for (int k = 0; k < KIN; k++) {
        float4 w4 = *(const float4*)&Wm[(size_t)k * HD_];
        float hk = hs[wave][k];
        a0 += hk * w4.x;
        a1 += hk * w4.y;
        a2 += hk * w4.z;
        a3 += hk * w4.w;
    }
    size_t fo = ((size_t)m * N_ + n) * HD_ + 4 * lane;
    ushort4 f4; f4.x = f2bf(a0); f4.y = f2bf(a1); f4.z = f2bf(a2); f4.w = f2bf(a3);
    *(ushort4*)&feat[fo] = f4;

    // el/er: head = lane/16 (cols 4l..4l+3 stay inside one head)
    const int head  = lane >> 4;
    const int dbase = (4 * lane) & 63;
    const float* alp = al + ((m * H_ + head) * D_ + dbase);
    const float* arp = ar + ((m * H_ + head) * D_ + dbase);
    float vl = a0 * alp[0] + a1 * alp[1] + a2 * alp[2] + a3 * alp[3];
    float vr = a0 * arp[0] + a1 * arp[1] + a2 * arp[2] + a3 * arp[3];
    for (int off = 8; off; off >>= 1) {
        vl += __shfl_down(vl, off, 16);
        vr += __shfl_down(vr, off, 16);
    }
    if ((lane & 15) == 0) {
        int o = (m * N_ + n) * H_ + head;
        el[o] = vl;
        er[o] = vr;
    }
}

// K2: per-edge scores: ee = exp(leaky_relu(el[src]+er[dst])), denom[dst] += ee
__global__ __launch_bounds__(256) void edge_scores(
    const int* __restrict__ src, const int* __restrict__ dst,
    const float* __restrict__ el, const float* __restrict__ er,
    float* __restrict__ ee, float* __restrict__ denom) {
    int i = blockIdx.x * 256 + threadIdx.x;        // m*E + e
    if (i >= M_ * E_) return;
    int m = i / E_;
    int s = src[i], d = dst[i];
    float4 l4 = *(const float4*)&el[(size_t)(m * N_ + s) * H_];
    float4 r4 = *(const float4*)&er[(size_t)(m * N_ + d) * H_];
    float x0 = l4.x + r4.x, x1 = l4.y + r4.y, x2 = l4.z + r4.z, x3 = l4.w + r4.w;
    x0 = x0 > 0.f ? x0 : NEG_SLOPE * x0;
    x1 = x1 > 0.f ? x1 : NEG_SLOPE * x1;
    x2 = x2 > 0.f ? x2 : NEG_SLOPE * x2;
    x3 = x3 > 0.f ? x3 : NEG_SLOPE * x3;
    // skip segment_max: exp(e)/sum(exp(e)) identical, scores are O(1) so no overflow
    float e0 = __expf(x0), e1 = __expf(x1), e2 = __expf(x2), e3 = __expf(x3);
    *(float4*)&ee[(size_t)i * H_] = make_float4(e0, e1, e2, e3);
    float* dn = &denom[(size_t)(m * N_ + d) * H_];
    atomicAdd(dn + 0, e0);
    atomicAdd(dn + 1, e1);
    atomicAdd(dn + 2, e2);
    atomicAdd(dn + 3, e3);
}

// K3: wave per edge: z[dst] += alpha * feat[src]  (4 cols per lane)
__global__ __launch_bounds__(256) void aggregate(
    const int* __restrict__ src, const int* __restrict__ dst,
    const float* __restrict__ ee, const float* __restrict__ denom,
    const ushort* __restrict__ feat, float* __restrict__ z) {
    int gw = blockIdx.x * 4 + (threadIdx.x >> 6);   // global edge index m*E+e
    if (gw >= M_ * E_) return;
    int lane = threadIdx.x & 63;
    int m = gw / E_;
    int s = src[gw], d = dst[gw];
    int head = lane >> 4;
    float den   = denom[(size_t)(m * N_ + d) * H_ + head];
    float alpha = ee[(size_t)gw * H_ + head] / fmaxf(den, 1e-9f);
    ushort4 f4 = *(const ushort4*)&feat[((size_t)m * N_ + s) * HD_ + 4 * lane];
    float* zd = z + ((size_t)m * N_ + d) * HD_ + 4 * lane;
    atomicAdd(zd + 0, alpha * bf2f(f4.x));
    atomicAdd(zd + 1, alpha * bf2f(f4.y));
    atomicAdd(zd + 2, alpha * bf2f(f4.z));
    atomicAdd(zd + 3, alpha * bf2f(f4.w));
}

// K4: block per node: w[n,m] = tanh(z_row @ W1 + b1) @ W2 ; wsum[m] += w
__global__ __launch_bounds__(128) void semantic_w(
    const float* __restrict__ z, const float* __restrict__ W1,
    const float* __restrict__ b1, const float* __restrict__ W2,
    float* __restrict__ wsum) {
    int n = blockIdx.x;
    int j = threadIdx.x;
    int lane = j & 63, wv = j >> 6;
    __shared__ float zrow[HD_];
    __shared__ float red[2];
    for (int m = 0; m < M_; m++) {
        __syncthreads();
        const float* zp = &z[((size_t)m * N_ + n) * HD_];
        zrow[j]       = zp[j];
        zrow[j + 128] = zp[j + 128];
        __syncthreads();
        float acc = b1[j];
#pragma unroll 8
        for (int c = 0; c < HD_; c++) acc += zrow[c] * W1[(size_t)c * HID_ + j];
        float contrib = tanhf(acc) * W2[j];
        for (int off = 32; off; off >>= 1) contrib += __shfl_down(contrib, off);
        if (lane == 0) red[wv] = contrib;
        __syncthreads();
        if (j == 0) atomicAdd(&wsum[m], red[0] + red[1]);
    }
}

// K5: beta = softmax(wsum / N)
__global__ void beta_kernel(const float* __restrict__ wsum, float* __restrict__ beta) {
    if (threadIdx.x == 0 && blockIdx.x == 0) {
        float w0 = wsum[0] / (float)N_, w1 = wsum[1] / (float)N_, w2 = wsum[2] / (float)N_;
        float mx = fmaxf(w0, fmaxf(w1, w2));
        float e0 = __expf(w0 - mx), e1 = __expf(w1 - mx), e2 = __expf(w2 - mx);
        float s = e0 + e1 + e2;
        beta[0] = e0 / s; beta[1] = e1 / s; beta[2] = e2 / s;
    }
}

// K6: out[n][c] = sum_m beta[m] * z[m][n][c], fp32 store
__global__ __launch_bounds__(256) void final_out(
    const float* __restrict__ z, const float* __restrict__ beta,
    float* __restrict__ out) {
    int idx = blockIdx.x * 256 + threadIdx.x;       // float4 index over [N*HD/4]
    if (idx >= N_ * HD_ / 4) return;
    float b0 = beta[0], b1 = beta[1], b2 = beta[2];
    float4 z0 = *(const float4*)&z[(size_t)idx * 4];
    float4 z1 = *(const float4*)&z[(size_t)N_ * HD_ + (size_t)idx * 4];
    float4 z2 = *(const float4*)&z[(size_t)2 * N_ * HD_ + (size_t)idx * 4];
    float4 o;
    o.x = b0 * z0.x + b1 * z1.x + b2 * z2.x;
    o.y = b0 * z0.y + b1 * z1.y + b2 * z2.y;
    o.z = b0 * z0.z + b1 * z1.z + b2 * z2.z;
    o.w = b0 * z0.w + b1 * z1.w + b2 * z2.w;
    *(float4*)&out[(size_t)idx * 4] = o;
}

extern "C" void kernel_launch(void* const* d_in, const int* in_sizes, int n_in,
                              void* d_out, int out_size, void* d_ws, size_t ws_size,
                              hipStream_t stream) {
    const float* h    = (const float*)d_in[0];
    const int*   src  = (const int*)d_in[1];
    const int*   dst  = (const int*)d_in[2];
    const float* W    = (const float*)d_in[3];
    const float* al   = (const float*)d_in[4];
    const float* ar   = (const float*)d_in[5];
    const float* bias = (const float*)d_in[6];
    const float* W1   = (const float*)d_in[7];
    const float* b1   = (const float*)d_in[8];
    const float* W2   = (const float*)d_in[9];

    char* ws = (char*)d_ws;
    ushort* feat = (ushort*)(ws + FEAT_OFF);
    float*  z    = (float*)(ws + Z_OFF);
    float*  el   = (float*)(ws + EL_OFF);
    float*  er   = (float*)(ws + ER_OFF);
    float*  ee   = (float*)(ws + EE_OFF);
    float*  den  = (float*)(ws + DEN_OFF);
    float*  wsum = (float*)(ws + WSUM_OFF);
    float*  beta = (float*)(ws + BETA_OFF);

    // zero denom + wsum (contiguous)
    hipMemsetAsync(ws + DEN_OFF, 0, 960000 + 64, stream);

    init_z<<<M_ * N_ * HD_ / 4 / 256, 256, 0, stream>>>(bias, z);
    feat_gemm<<<dim3(N_ / 4, M_), 256, 0, stream>>>(h, W, al, ar, feat, el, er);
    edge_scores<<<(M_ * E_) / 256, 256, 0, stream>>>(src, dst, el, er, ee, den);
    aggregate<<<(M_ * E_) / 4, 256, 0, stream>>>(src, dst, ee, den, feat, z);
    semantic_w<<<N_, 128, 0, stream>>>(z, W1, b1, W2, wsum);
    beta_kernel<<<1, 64, 0, stream>>>(wsum, beta);
    final_out<<<N_ * HD_ / 4 / 256, 256, 0, stream>>>(z, beta, (float*)d_out);
}

// Round 3
// 1437.902 us; speedup vs baseline: 3.1250x; 3.1250x over previous
//
#include <hip/hip_runtime.h>
#include <hip/hip_bf16.h>

// Problem constants
constexpr int N_   = 20000;
constexpr int E_   = 320000;
constexpr int M_   = 3;
constexpr int KIN  = 128;   // in_size
constexpr int H_   = 4;     // heads
constexpr int D_   = 64;    // per-head dim
constexpr int HD_  = 256;   // H*D
constexpr int HID_ = 128;   // semantic hidden
constexpr int MN_  = M_ * N_;   // 60000 segments
constexpr int ME_  = M_ * E_;   // 960000 edges
#define NEG_SLOPE 0.2f

// Workspace layout (bytes) — ~98.6 MB
constexpr size_t FEAT_OFF = 0;           // ushort[M*N*HD]  = 30,720,000 (internal bf16 feat)
constexpr size_t Z_OFF    = 30720000;    // float [M*N*HD]  = 61,440,000
constexpr size_t EL_OFF   = 92160000;    // float [M*N*H]   =    960,000
constexpr size_t ER_OFF   = 93120000;    // float [M*N*H]   =    960,000
constexpr size_t ESRC_OFF = 94080000;    // int   [M*E]     =  3,840,000 (CSR-ordered src ids)
constexpr size_t ROW_OFF  = 97920000;    // int   [MN+1]    =    240,064 (padded)
constexpr size_t CUR_OFF  = 98160064;    // int   [MN]      =    240,000 (scatter cursors)
constexpr size_t CNT_OFF  = 98400064;    // int   [MN]      =    240,000 (histogram)  } memset
constexpr size_t WSUM_OFF = 98640064;    // float [16]                               } together
constexpr size_t BETA_OFF = 98640128;    // float [16]

__device__ __forceinline__ float bf2f(ushort u) {
    union { unsigned int i; float f; } v; v.i = ((unsigned int)u) << 16; return v.f;
}
__device__ __forceinline__ ushort f2bf(float f) {
    union { float f; unsigned int i; } v; v.f = f;
    unsigned int i = v.i;
    unsigned int r = (i + 0x7fffu + ((i >> 16) & 1u)) >> 16;   // RNE
    return (ushort)r;
}

// K1: feat = h @ W[m] (bf16 store, internal) + fused el/er epilogue.
// Block = 256 = 4 waves; wave -> one node; lane handles cols 4l..4l+3.
__global__ __launch_bounds__(256) void feat_gemm(
    const float* __restrict__ h, const float* __restrict__ W,
    const float* __restrict__ al, const float* __restrict__ ar,
    ushort* __restrict__ feat, float* __restrict__ el, float* __restrict__ er) {
    const int m    = blockIdx.y;
    const int wave = threadIdx.x >> 6;
    const int lane = threadIdx.x & 63;
    const int n    = blockIdx.x * 4 + wave;

    __shared__ float hs[4][KIN];
    {
        float2 p = *(const float2*)&h[(size_t)n * KIN + 2 * lane];
        hs[wave][2 * lane]     = p.x;
        hs[wave][2 * lane + 1] = p.y;
    }
    __syncthreads();

    const float* Wm = W + (size_t)m * KIN * HD_ + 4 * lane;
    float a0 = 0.f, a1 = 0.f, a2 = 0.f, a3 = 0.f;
#pragma unroll 8
    for (int k = 0; k < KIN; k++) {
        float4 w4 = *(const float4*)&Wm[(size_t)k * HD_];
        float hk = hs[wave][k];
        a0 += hk * w4.x;
        a1 += hk * w4.y;
        a2 += hk * w4.z;
        a3 += hk * w4.w;
    }
    size_t fo = ((size_t)m * N_ + n) * HD_ + 4 * lane;
    ushort4 f4; f4.x = f2bf(a0); f4.y = f2bf(a1); f4.z = f2bf(a2); f4.w = f2bf(a3);
    *(ushort4*)&feat[fo] = f4;

    // el/er: head = lane/16 (cols 4l..4l+3 stay inside one head)
    const int head  = lane >> 4;
    const int dbase = (4 * lane) & 63;
    const float* alp = al + ((m * H_ + head) * D_ + dbase);
    const float* arp = ar + ((m * H_ + head) * D_ + dbase);
    float vl = a0 * alp[0] + a1 * alp[1] + a2 * alp[2] + a3 * alp[3];
    float vr = a0 * arp[0] + a1 * arp[1] + a2 * arp[2] + a3 * arp[3];
    for (int off = 8; off; off >>= 1) {
        vl += __shfl_down(vl, off, 16);
        vr += __shfl_down(vr, off, 16);
    }
    if ((lane & 15) == 0) {
        int o = (m * N_ + n) * H_ + head;
        el[o] = vl;
        er[o] = vr;
    }
}

// K2: in-degree histogram over (m, dst)
__global__ __launch_bounds__(256) void hist_kernel(const int* __restrict__ dst,
                                                   int* __restrict__ cnt) {
    int i = blockIdx.x * 256 + threadIdx.x;
    if (i >= ME_) return;
    int m = i / E_;
    atomicAdd(&cnt[m * N_ + dst[i]], 1);
}

// K3: single-block exclusive scan over cnt[MN] -> rowstart[MN+1], cursor[MN]
__global__ __launch_bounds__(1024) void scan_kernel(const int* __restrict__ cnt,
                                                    int* __restrict__ rowstart,
                                                    int* __restrict__ cursor) {
    __shared__ int lds[1024];
    const int t  = threadIdx.x;
    const int CH = (MN_ + 1023) / 1024;            // 59
    const int b  = t * CH;
    const int e  = min(b + CH, MN_);
    int sum = 0;
    for (int i = b; i < e; i++) sum += cnt[i];
    lds[t] = sum;
    for (int s = 1; s < 1024; s <<= 1) {
        __syncthreads();
        int v = (t >= s) ? lds[t - s] : 0;
        __syncthreads();
        lds[t] += v;
    }
    __syncthreads();
    int run = lds[t] - sum;                        // exclusive prefix of this chunk
    for (int i = b; i < e; i++) {
        rowstart[i] = run;
        cursor[i]   = run;
        run += cnt[i];
    }
    if (t == 1023) rowstart[MN_] = lds[1023];
}

// K4: scatter edge src ids into CSR order
__global__ __launch_bounds__(256) void scatter_kernel(const int* __restrict__ src,
                                                      const int* __restrict__ dst,
                                                      int* __restrict__ cursor,
                                                      int* __restrict__ esrc) {
    int i = blockIdx.x * 256 + threadIdx.x;
    if (i >= ME_) return;
    int m = i / E_;
    int pos = atomicAdd(&cursor[m * N_ + dst[i]], 1);
    esrc[pos] = src[i];
}

// K5: wave per (m, dst): single-pass softmax-weighted aggregation.
//   z = (sum_j ee_j * feat[src_j]) / (sum_j ee_j) + bias      (ee recomputed on the fly)
__global__ __launch_bounds__(256) void aggregate_csr(
    const int* __restrict__ rowstart, const int* __restrict__ esrc,
    const float* __restrict__ el, const float* __restrict__ er,
    const ushort* __restrict__ feat, const float* __restrict__ bias,
    float* __restrict__ z) {
    const int g = blockIdx.x * 4 + (threadIdx.x >> 6);   // m*N + n, grid covers exactly MN_
    const int lane = threadIdx.x & 63;
    const int m = g / N_;
    const int head = lane >> 4;
    const int beg = rowstart[g], end = rowstart[g + 1];
    const float erv = er[(size_t)g * H_ + head];         // wave-constant per head group
    const int mN = m * N_;
    const ushort* fm = feat + (size_t)mN * HD_;
    float a0 = 0.f, a1 = 0.f, a2 = 0.f, a3 = 0.f, den = 0.f;
    for (int j = beg; j < end; j++) {
        int s = esrc[j];
        float x = el[(size_t)(mN + s) * H_ + head] + erv;
        x = x > 0.f ? x : NEG_SLOPE * x;
        float ee = __expf(x);
        ushort4 f4 = *(const ushort4*)&fm[(size_t)s * HD_ + 4 * lane];
        a0 += ee * bf2f(f4.x);
        a1 += ee * bf2f(f4.y);
        a2 += ee * bf2f(f4.z);
        a3 += ee * bf2f(f4.w);
        den += ee;
    }
    float inv = 1.f / fmaxf(den, 1e-9f);
    float4 b4 = *(const float4*)&bias[m * HD_ + 4 * lane];
    float4 o;
    o.x = a0 * inv + b4.x;
    o.y = a1 * inv + b4.y;
    o.z = a2 * inv + b4.z;
    o.w = a3 * inv + b4.w;
    *(float4*)&z[(size_t)g * HD_ + 4 * lane] = o;
}

// K6: block per node: w[n,m] = tanh(z_row @ W1 + b1) @ W2 ; wsum[m] += w
__global__ __launch_bounds__(128) void semantic_w(
    const float* __restrict__ z, const float* __restrict__ W1,
    const float* __restrict__ b1, const float* __restrict__ W2,
    float* __restrict__ wsum) {
    int n = blockIdx.x;
    int j = threadIdx.x;
    int lane = j & 63, wv = j >> 6;
    __shared__ float zrow[HD_];
    __shared__ float red[2];
    for (int m = 0; m < M_; m++) {
        __syncthreads();
        const float* zp = &z[((size_t)m * N_ + n) * HD_];
        zrow[j]       = zp[j];
        zrow[j + 128] = zp[j + 128];
        __syncthreads();
        float acc = b1[j];
#pragma unroll 8
        for (int c = 0; c < HD_; c++) acc += zrow[c] * W1[(size_t)c * HID_ + j];
        float contrib = tanhf(acc) * W2[j];
        for (int off = 32; off; off >>= 1) contrib += __shfl_down(contrib, off);
        if (lane == 0) red[wv] = contrib;
        __syncthreads();
        if (j == 0) atomicAdd(&wsum[m], red[0] + red[1]);
    }
}

// K7: beta = softmax(wsum / N)
__global__ void beta_kernel(const float* __restrict__ wsum, float* __restrict__ beta) {
    if (threadIdx.x == 0 && blockIdx.x == 0) {
        float w0 = wsum[0] / (float)N_, w1 = wsum[1] / (float)N_, w2 = wsum[2] / (float)N_;
        float mx = fmaxf(w0, fmaxf(w1, w2));
        float e0 = __expf(w0 - mx), e1 = __expf(w1 - mx), e2 = __expf(w2 - mx);
        float s = e0 + e1 + e2;
        beta[0] = e0 / s; beta[1] = e1 / s; beta[2] = e2 / s;
    }
}

// K8: out[n][c] = sum_m beta[m] * z[m][n][c], fp32 store
__global__ __launch_bounds__(256) void final_out(
    const float* __restrict__ z, const float* __restrict__ beta,
    float* __restrict__ out) {
    int idx = blockIdx.x * 256 + threadIdx.x;       // float4 index over [N*HD/4]
    if (idx >= N_ * HD_ / 4) return;
    float b0 = beta[0], b1 = beta[1], b2 = beta[2];
    float4 z0 = *(const float4*)&z[(size_t)idx * 4];
    float4 z1 = *(const float4*)&z[(size_t)N_ * HD_ + (size_t)idx * 4];
    float4 z2 = *(const float4*)&z[(size_t)2 * N_ * HD_ + (size_t)idx * 4];
    float4 o;
    o.x = b0 * z0.x + b1 * z1.x + b2 * z2.x;
    o.y = b0 * z0.y + b1 * z1.y + b2 * z2.y;
    o.z = b0 * z0.z + b1 * z1.z + b2 * z2.z;
    o.w = b0 * z0.w + b1 * z1.w + b2 * z2.w;
    *(float4*)&out[(size_t)idx * 4] = o;
}

extern "C" void kernel_launch(void* const* d_in, const int* in_sizes, int n_in,
                              void* d_out, int out_size, void* d_ws, size_t ws_size,
                              hipStream_t stream) {
    const float* h    = (const float*)d_in[0];
    const int*   src  = (const int*)d_in[1];
    const int*   dst  = (const int*)d_in[2];
    const float* W    = (const float*)d_in[3];
    const float* al   = (const float*)d_in[4];
    const float* ar   = (const float*)d_in[5];
    const float* bias = (const float*)d_in[6];
    const float* W1   = (const float*)d_in[7];
    const float* b1   = (const float*)d_in[8];
    const float* W2   = (const float*)d_in[9];

    char* ws = (char*)d_ws;
    ushort* feat     = (ushort*)(ws + FEAT_OFF);
    float*  z        = (float*)(ws + Z_OFF);
    float*  el       = (float*)(ws + EL_OFF);
    float*  er       = (float*)(ws + ER_OFF);
    int*    esrc     = (int*)(ws + ESRC_OFF);
    int*    rowstart = (int*)(ws + ROW_OFF);
    int*    cursor   = (int*)(ws + CUR_OFF);
    int*    cnt      = (int*)(ws + CNT_OFF);
    float*  wsum     = (float*)(ws + WSUM_OFF);
    float*  beta     = (float*)(ws + BETA_OFF);

    // zero cnt + wsum (contiguous)
    hipMemsetAsync(ws + CNT_OFF, 0, 240000 + 64, stream);

    feat_gemm<<<dim3(N_ / 4, M_), 256, 0, stream>>>(h, W, al, ar, feat, el, er);
    hist_kernel<<<(ME_ + 255) / 256, 256, 0, stream>>>(dst, cnt);
    scan_kernel<<<1, 1024, 0, stream>>>(cnt, rowstart, cursor);
    scatter_kernel<<<(ME_ + 255) / 256, 256, 0, stream>>>(src, dst, cursor, esrc);
    aggregate_csr<<<MN_ / 4, 256, 0, stream>>>(rowstart, esrc, el, er, feat, bias, z);
    semantic_w<<<N_, 128, 0, stream>>>(z, W1, b1, W2, wsum);
    beta_kernel<<<1, 64, 0, stream>>>(wsum, beta);
    final_out<<<N_ * HD_ / 4 / 256, 256, 0, stream>>>(z, beta, (float*)d_out);
}

// Round 4
// 705.809 us; speedup vs baseline: 6.3664x; 2.0372x over previous
//
#include <hip/hip_runtime.h>
#include <hip/hip_bf16.h>

// Problem constants
constexpr int N_   = 20000;
constexpr int E_   = 320000;
constexpr int M_   = 3;
constexpr int KIN  = 128;   // in_size
constexpr int H_   = 4;     // heads
constexpr int D_   = 64;    // per-head dim
constexpr int HD_  = 256;   // H*D
constexpr int HID_ = 128;   // semantic hidden
constexpr int MN_  = M_ * N_;   // 60000 segments
constexpr int ME_  = M_ * E_;   // 960000 edges
#define NEG_SLOPE 0.2f

// Workspace layout (bytes) — ~98.6 MB
constexpr size_t FEAT_OFF = 0;           // ushort[M*N*HD]  = 30,720,000 (internal bf16 feat)
constexpr size_t Z_OFF    = 30720000;    // float [M*N*HD]  = 61,440,000
constexpr size_t EL_OFF   = 92160000;    // float [M*N*H]   =    960,000
constexpr size_t ER_OFF   = 93120000;    // float [M*N*H]   =    960,000
constexpr size_t ESRC_OFF = 94080000;    // int   [M*E]     =  3,840,000 (CSR-ordered src ids)
constexpr size_t ROW_OFF  = 97920000;    // int   [MN+1]    =    240,064 (padded)
constexpr size_t CUR_OFF  = 98160064;    // int   [MN]      =    240,000 (scatter cursors)
constexpr size_t CNT_OFF  = 98400064;    // int   [MN]      =    240,000 (histogram)  } memset
constexpr size_t WSUM_OFF = 98640064;    // float [16]                               } together
constexpr size_t BETA_OFF = 98640128;    // float [16]

__device__ __forceinline__ float bf2f(ushort u) {
    union { unsigned int i; float f; } v; v.i = ((unsigned int)u) << 16; return v.f;
}
__device__ __forceinline__ ushort f2bf(float f) {
    union { float f; unsigned int i; } v; v.f = f;
    unsigned int i = v.i;
    unsigned int r = (i + 0x7fffu + ((i >> 16) & 1u)) >> 16;   // RNE
    return (ushort)r;
}

// K1: feat = h @ W[m] (bf16 store, internal) + fused el/er epilogue.
// Block = 256 = 4 waves; wave -> one node; lane handles cols 4l..4l+3.
__global__ __launch_bounds__(256) void feat_gemm(
    const float* __restrict__ h, const float* __restrict__ W,
    const float* __restrict__ al, const float* __restrict__ ar,
    ushort* __restrict__ feat, float* __restrict__ el, float* __restrict__ er) {
    const int m    = blockIdx.y;
    const int wave = threadIdx.x >> 6;
    const int lane = threadIdx.x & 63;
    const int n    = blockIdx.x * 4 + wave;

    __shared__ float hs[4][KIN];
    {
        float2 p = *(const float2*)&h[(size_t)n * KIN + 2 * lane];
        hs[wave][2 * lane]     = p.x;
        hs[wave][2 * lane + 1] = p.y;
    }
    __syncthreads();

    const float* Wm = W + (size_t)m * KIN * HD_ + 4 * lane;
    float a0 = 0.f, a1 = 0.f, a2 = 0.f, a3 = 0.f;
#pragma unroll 8
    for (int k = 0; k < KIN; k++) {
        float4 w4 = *(const float4*)&Wm[(size_t)k * HD_];
        float hk = hs[wave][k];
        a0 += hk * w4.x;
        a1 += hk * w4.y;
        a2 += hk * w4.z;
        a3 += hk * w4.w;
    }
    size_t fo = ((size_t)m * N_ + n) * HD_ + 4 * lane;
    ushort4 f4; f4.x = f2bf(a0); f4.y = f2bf(a1); f4.z = f2bf(a2); f4.w = f2bf(a3);
    *(ushort4*)&feat[fo] = f4;

    // el/er: head = lane/16 (cols 4l..4l+3 stay inside one head)
    const int head  = lane >> 4;
    const int dbase = (4 * lane) & 63;
    const float* alp = al + ((m * H_ + head) * D_ + dbase);
    const float* arp = ar + ((m * H_ + head) * D_ + dbase);
    float vl = a0 * alp[0] + a1 * alp[1] + a2 * alp[2] + a3 * alp[3];
    float vr = a0 * arp[0] + a1 * arp[1] + a2 * arp[2] + a3 * arp[3];
    for (int off = 8; off; off >>= 1) {
        vl += __shfl_down(vl, off, 16);
        vr += __shfl_down(vr, off, 16);
    }
    if ((lane & 15) == 0) {
        int o = (m * N_ + n) * H_ + head;
        el[o] = vl;
        er[o] = vr;
    }
}

// K2: in-degree histogram over (m, dst)
__global__ __launch_bounds__(256) void hist_kernel(const int* __restrict__ dst,
                                                   int* __restrict__ cnt) {
    int i = blockIdx.x * 256 + threadIdx.x;
    if (i >= ME_) return;
    int m = i / E_;
    atomicAdd(&cnt[m * N_ + dst[i]], 1);
}

// K3: single-block exclusive scan over cnt[MN] -> rowstart[MN+1], cursor[MN]
__global__ __launch_bounds__(1024) void scan_kernel(const int* __restrict__ cnt,
                                                    int* __restrict__ rowstart,
                                                    int* __restrict__ cursor) {
    __shared__ int lds[1024];
    const int t  = threadIdx.x;
    const int CH = (MN_ + 1023) / 1024;            // 59
    const int b  = t * CH;
    const int e  = min(b + CH, MN_);
    int sum = 0;
    for (int i = b; i < e; i++) sum += cnt[i];
    lds[t] = sum;
    for (int s = 1; s < 1024; s <<= 1) {
        __syncthreads();
        int v = (t >= s) ? lds[t - s] : 0;
        __syncthreads();
        lds[t] += v;
    }
    __syncthreads();
    int run = lds[t] - sum;                        // exclusive prefix of this chunk
    for (int i = b; i < e; i++) {
        rowstart[i] = run;
        cursor[i]   = run;
        run += cnt[i];
    }
    if (t == 1023) rowstart[MN_] = lds[1023];
}

// K4: scatter edge src ids into CSR order
__global__ __launch_bounds__(256) void scatter_kernel(const int* __restrict__ src,
                                                      const int* __restrict__ dst,
                                                      int* __restrict__ cursor,
                                                      int* __restrict__ esrc) {
    int i = blockIdx.x * 256 + threadIdx.x;
    if (i >= ME_) return;
    int m = i / E_;
    int pos = atomicAdd(&cursor[m * N_ + dst[i]], 1);
    esrc[pos] = src[i];
}

// K5: wave per (m, dst): single-pass softmax-weighted aggregation.
//   z = (sum_j ee_j * feat[src_j]) / (sum_j ee_j) + bias      (ee recomputed on the fly)
__global__ __launch_bounds__(256) void aggregate_csr(
    const int* __restrict__ rowstart, const int* __restrict__ esrc,
    const float* __restrict__ el, const float* __restrict__ er,
    const ushort* __restrict__ feat, const float* __restrict__ bias,
    float* __restrict__ z) {
    const int g = blockIdx.x * 4 + (threadIdx.x >> 6);   // m*N + n, grid covers exactly MN_
    const int lane = threadIdx.x & 63;
    const int m = g / N_;
    const int head = lane >> 4;
    const int beg = rowstart[g], end = rowstart[g + 1];
    const float erv = er[(size_t)g * H_ + head];         // wave-constant per head group
    const int mN = m * N_;
    const ushort* fm = feat + (size_t)mN * HD_;
    float a0 = 0.f, a1 = 0.f, a2 = 0.f, a3 = 0.f, den = 0.f;
    for (int j = beg; j < end; j++) {
        int s = esrc[j];
        float x = el[(size_t)(mN + s) * H_ + head] + erv;
        x = x > 0.f ? x : NEG_SLOPE * x;
        float ee = __expf(x);
        ushort4 f4 = *(const ushort4*)&fm[(size_t)s * HD_ + 4 * lane];
        a0 += ee * bf2f(f4.x);
        a1 += ee * bf2f(f4.y);
        a2 += ee * bf2f(f4.z);
        a3 += ee * bf2f(f4.w);
        den += ee;
    }
    float inv = 1.f / fmaxf(den, 1e-9f);
    float4 b4 = *(const float4*)&bias[m * HD_ + 4 * lane];
    float4 o;
    o.x = a0 * inv + b4.x;
    o.y = a1 * inv + b4.y;
    o.z = a2 * inv + b4.z;
    o.w = a3 * inv + b4.w;
    *(float4*)&z[(size_t)g * HD_ + 4 * lane] = o;
}

// K6: tiled GEMM semantic attention.
// Block = 256 threads computes a 32-row x 128-col tile of tanh(z@W1+b1),
// dots with W2, reduces, one atomicAdd per block into wsum[m].
// 60000 rows, 32/block -> 1875 blocks; 20000 % 32 == 0 so tiles never straddle m.
constexpr int SR_ = 32;   // rows per block
constexpr int SK_ = 32;   // K chunk
__global__ __launch_bounds__(256) void semantic_w(
    const float* __restrict__ z, const float* __restrict__ W1,
    const float* __restrict__ b1, const float* __restrict__ W2,
    float* __restrict__ wsum) {
    const int tx = threadIdx.x;
    const int rowbase = blockIdx.x * SR_;           // global row (m*N+n)
    const int m = rowbase / N_;
    const int col4 = (tx & 31) * 4;                 // cols col4..col4+3
    const int row4 = (tx >> 5) * 4;                 // rows row4..row4+3 (local)

    __shared__ float zs[SK_][SR_ + 4];              // transposed z tile (pad keeps fp4 align)
    __shared__ float w1s[SK_][HID_];                // W1 tile
    __shared__ float red[4];

    float acc[4][4];
#pragma unroll
    for (int i = 0; i < 4; i++)
#pragma unroll
        for (int j = 0; j < 4; j++) acc[i][j] = 0.f;

    const int lr = tx >> 3;                         // load row 0..31
    const int lk = (tx & 7) * 4;                    // load k offset 0,4,..28

    for (int k0 = 0; k0 < HD_; k0 += SK_) {
        // stage z tile transposed: zs[k][row]
        float4 zv = *(const float4*)&z[((size_t)(rowbase + lr)) * HD_ + k0 + lk];
        zs[lk + 0][lr] = zv.x;
        zs[lk + 1][lr] = zv.y;
        zs[lk + 2][lr] = zv.z;
        zs[lk + 3][lr] = zv.w;
        // stage W1 tile: w1s[k][col], contiguous copy of 4096 floats
#pragma unroll
        for (int i = 0; i < 4; i++) {
            int idx = (tx + i * 256) * 4;           // float index 0..16380
            *(float4*)&w1s[0][idx] = *(const float4*)&W1[(size_t)k0 * HID_ + idx];
        }
        __syncthreads();
#pragma unroll
        for (int k = 0; k < SK_; k++) {
            float4 za = *(const float4*)&zs[k][row4];
            float4 wa = *(const float4*)&w1s[k][col4];
            acc[0][0] += za.x * wa.x; acc[0][1] += za.x * wa.y; acc[0][2] += za.x * wa.z; acc[0][3] += za.x * wa.w;
            acc[1][0] += za.y * wa.x; acc[1][1] += za.y * wa.y; acc[1][2] += za.y * wa.z; acc[1][3] += za.y * wa.w;
            acc[2][0] += za.z * wa.x; acc[2][1] += za.z * wa.y; acc[2][2] += za.z * wa.z; acc[2][3] += za.z * wa.w;
            acc[3][0] += za.w * wa.x; acc[3][1] += za.w * wa.y; acc[3][2] += za.w * wa.z; acc[3][3] += za.w * wa.w;
        }
        __syncthreads();
    }

    // epilogue: sum_j tanh(acc + b1[col]) * W2[col] over this thread's 4x4
    float4 bb = *(const float4*)&b1[col4];
    float4 w2 = *(const float4*)&W2[col4];
    float local = 0.f;
#pragma unroll
    for (int i = 0; i < 4; i++) {
        local += tanhf(acc[i][0] + bb.x) * w2.x;
        local += tanhf(acc[i][1] + bb.y) * w2.y;
        local += tanhf(acc[i][2] + bb.z) * w2.z;
        local += tanhf(acc[i][3] + bb.w) * w2.w;
    }
    for (int off = 32; off; off >>= 1) local += __shfl_down(local, off);
    if ((tx & 63) == 0) red[tx >> 6] = local;
    __syncthreads();
    if (tx == 0) atomicAdd(&wsum[m], red[0] + red[1] + red[2] + red[3]);
}

// K7: beta = softmax(wsum / N)
__global__ void beta_kernel(const float* __restrict__ wsum, float* __restrict__ beta) {
    if (threadIdx.x == 0 && blockIdx.x == 0) {
        float w0 = wsum[0] / (float)N_, w1 = wsum[1] / (float)N_, w2 = wsum[2] / (float)N_;
        float mx = fmaxf(w0, fmaxf(w1, w2));
        float e0 = __expf(w0 - mx), e1 = __expf(w1 - mx), e2 = __expf(w2 - mx);
        float s = e0 + e1 + e2;
        beta[0] = e0 / s; beta[1] = e1 / s; beta[2] = e2 / s;
    }
}

// K8: out[n][c] = sum_m beta[m] * z[m][n][c], fp32 store
__global__ __launch_bounds__(256) void final_out(
    const float* __restrict__ z, const float* __restrict__ beta,
    float* __restrict__ out) {
    int idx = blockIdx.x * 256 + threadIdx.x;       // float4 index over [N*HD/4]
    if (idx >= N_ * HD_ / 4) return;
    float b0 = beta[0], b1 = beta[1], b2 = beta[2];
    float4 z0 = *(const float4*)&z[(size_t)idx * 4];
    float4 z1 = *(const float4*)&z[(size_t)N_ * HD_ + (size_t)idx * 4];
    float4 z2 = *(const float4*)&z[(size_t)2 * N_ * HD_ + (size_t)idx * 4];
    float4 o;
    o.x = b0 * z0.x + b1 * z1.x + b2 * z2.x;
    o.y = b0 * z0.y + b1 * z1.y + b2 * z2.y;
    o.z = b0 * z0.z + b1 * z1.z + b2 * z2.z;
    o.w = b0 * z0.w + b1 * z1.w + b2 * z2.w;
    *(float4*)&out[(size_t)idx * 4] = o;
}

extern "C" void kernel_launch(void* const* d_in, const int* in_sizes, int n_in,
                              void* d_out, int out_size, void* d_ws, size_t ws_size,
                              hipStream_t stream) {
    const float* h    = (const float*)d_in[0];
    const int*   src  = (const int*)d_in[1];
    const int*   dst  = (const int*)d_in[2];
    const float* W    = (const float*)d_in[3];
    const float* al   = (const float*)d_in[4];
    const float* ar   = (const float*)d_in[5];
    const float* bias = (const float*)d_in[6];
    const float* W1   = (const float*)d_in[7];
    const float* b1   = (const float*)d_in[8];
    const float* W2   = (const float*)d_in[9];

    char* ws = (char*)d_ws;
    ushort* feat     = (ushort*)(ws + FEAT_OFF);
    float*  z        = (float*)(ws + Z_OFF);
    float*  el       = (float*)(ws + EL_OFF);
    float*  er       = (float*)(ws + ER_OFF);
    int*    esrc     = (int*)(ws + ESRC_OFF);
    int*    rowstart = (int*)(ws + ROW_OFF);
    int*    cursor   = (int*)(ws + CUR_OFF);
    int*    cnt      = (int*)(ws + CNT_OFF);
    float*  wsum     = (float*)(ws + WSUM_OFF);
    float*  beta     = (float*)(ws + BETA_OFF);

    // zero cnt + wsum (contiguous)
    hipMemsetAsync(ws + CNT_OFF, 0, 240000 + 64, stream);

    feat_gemm<<<dim3(N_ / 4, M_), 256, 0, stream>>>(h, W, al, ar, feat, el, er);
    hist_kernel<<<(ME_ + 255) / 256, 256, 0, stream>>>(dst, cnt);
    scan_kernel<<<1, 1024, 0, stream>>>(cnt, rowstart, cursor);
    scatter_kernel<<<(ME_ + 255) / 256, 256, 0, stream>>>(src, dst, cursor, esrc);
    aggregate_csr<<<MN_ / 4, 256, 0, stream>>>(rowstart, esrc, el, er, feat, bias, z);
    semantic_w<<<MN_ / SR_, 256, 0, stream>>>(z, W1, b1, W2, wsum);
    beta_kernel<<<1, 64, 0, stream>>>(wsum, beta);
    final_out<<<N_ * HD_ / 4 / 256, 256, 0, stream>>>(z, beta, (float*)d_out);
}

// Round 5
// 550.628 us; speedup vs baseline: 8.1606x; 1.2818x over previous
//
#include <hip/hip_runtime.h>
#include <hip/hip_bf16.h>

// Problem constants
constexpr int N_   = 20000;
constexpr int E_   = 320000;
constexpr int M_   = 3;
constexpr int KIN  = 128;   // in_size
constexpr int H_   = 4;     // heads
constexpr int D_   = 64;    // per-head dim
constexpr int HD_  = 256;   // H*D
constexpr int HID_ = 128;   // semantic hidden
constexpr int MN_  = M_ * N_;   // 60000 segments
constexpr int ME_  = M_ * E_;   // 960000 edges
#define NEG_SLOPE 0.2f

// Workspace layout (bytes) — ~98.6 MB
constexpr size_t FEAT_OFF = 0;           // ushort[M*N*HD]  = 30,720,000 (internal bf16 feat)
constexpr size_t Z_OFF    = 30720000;    // float [M*N*HD]  = 61,440,000
constexpr size_t EL_OFF   = 92160000;    // float [M*N*H]   =    960,000
constexpr size_t ER_OFF   = 93120000;    // float [M*N*H]   =    960,000
constexpr size_t ESRC_OFF = 94080000;    // int   [M*E]     =  3,840,000 (CSR-ordered src ids)
constexpr size_t ROW_OFF  = 97920000;    // int   [MN+1]    =    240,064 (padded)
constexpr size_t CUR_OFF  = 98160064;    // int   [MN]      =    240,000 (scatter cursors)
constexpr size_t CNT_OFF  = 98400064;    // int   [MN]      =    240,000 (histogram)  } memset
constexpr size_t WSUM_OFF = 98640064;    // float [16]                               } together
constexpr size_t BETA_OFF = 98640128;    // float [16]

__device__ __forceinline__ float bf2f(ushort u) {
    union { unsigned int i; float f; } v; v.i = ((unsigned int)u) << 16; return v.f;
}
__device__ __forceinline__ ushort f2bf(float f) {
    union { float f; unsigned int i; } v; v.f = f;
    unsigned int i = v.i;
    unsigned int r = (i + 0x7fffu + ((i >> 16) & 1u)) >> 16;   // RNE
    return (ushort)r;
}

// K1: feat = h @ W[m] (bf16 store) + fused el/er epilogue — register-tiled GEMM.
// Block = 256 threads computes a 32-node x 128-col tile; grid (625, 6):
//   m = blockIdx.y >> 1, colbase = (blockIdx.y & 1) * 128.
// Thread (tx): rows row4..row4+3 (row4 = (tx>>5)*4), cols col4..col4+3
// (col4 = (tx&31)*4). K staged in 32-chunks via LDS.
__global__ __launch_bounds__(256) void feat_gemm(
    const float* __restrict__ h, const float* __restrict__ W,
    const float* __restrict__ al, const float* __restrict__ ar,
    ushort* __restrict__ feat, float* __restrict__ el, float* __restrict__ er) {
    const int tx      = threadIdx.x;
    const int rowbase = blockIdx.x * 32;            // node base
    const int m       = blockIdx.y >> 1;
    const int colbase = (blockIdx.y & 1) * 128;
    const int col4    = (tx & 31) * 4;              // col within 128-tile
    const int row4    = (tx >> 5) * 4;              // local row

    __shared__ float hs[32][36];                    // transposed h tile [k][row], +4 pad
    __shared__ float ws_[32][128];                  // W tile [k][col]

    float acc[4][4];
#pragma unroll
    for (int i = 0; i < 4; i++)
#pragma unroll
        for (int j = 0; j < 4; j++) acc[i][j] = 0.f;

    const int lr = tx >> 3;                         // load row 0..31
    const int lk = (tx & 7) * 4;                    // load k offset 0,4,..28

    for (int k0 = 0; k0 < KIN; k0 += 32) {
        float4 hv = *(const float4*)&h[(size_t)(rowbase + lr) * KIN + k0 + lk];
        hs[lk + 0][lr] = hv.x;
        hs[lk + 1][lr] = hv.y;
        hs[lk + 2][lr] = hv.z;
        hs[lk + 3][lr] = hv.w;
#pragma unroll
        for (int i = 0; i < 4; i++) {
            int idx = (tx + i * 256) * 4;           // float index 0..4092 in 32x128 tile
            int kk  = idx >> 7, cc = idx & 127;
            *(float4*)&ws_[kk][cc] =
                *(const float4*)&W[(size_t)m * KIN * HD_ + (size_t)(k0 + kk) * HD_ + colbase + cc];
        }
        __syncthreads();
#pragma unroll
        for (int k = 0; k < 32; k++) {
            float4 za = *(const float4*)&hs[k][row4];
            float4 wa = *(const float4*)&ws_[k][col4];
            acc[0][0] += za.x * wa.x; acc[0][1] += za.x * wa.y; acc[0][2] += za.x * wa.z; acc[0][3] += za.x * wa.w;
            acc[1][0] += za.y * wa.x; acc[1][1] += za.y * wa.y; acc[1][2] += za.y * wa.z; acc[1][3] += za.y * wa.w;
            acc[2][0] += za.z * wa.x; acc[2][1] += za.z * wa.y; acc[2][2] += za.z * wa.z; acc[2][3] += za.z * wa.w;
            acc[3][0] += za.w * wa.x; acc[3][1] += za.w * wa.y; acc[3][2] += za.w * wa.z; acc[3][3] += za.w * wa.w;
        }
        __syncthreads();
    }

    // store feat (bf16): 4 rows x 4 cols
#pragma unroll
    for (int i = 0; i < 4; i++) {
        size_t fo = ((size_t)m * N_ + rowbase + row4 + i) * HD_ + colbase + col4;
        ushort4 f4;
        f4.x = f2bf(acc[i][0]); f4.y = f2bf(acc[i][1]);
        f4.z = f2bf(acc[i][2]); f4.w = f2bf(acc[i][3]);
        *(ushort4*)&feat[fo] = f4;
    }

    // el/er epilogue: head = (colbase+col4)/64; this thread's 4 cols stay in one head.
    // The 16 lanes with the same (tx>>4) cover the head's full 64 cols.
    const int head = (colbase + col4) >> 6;
    const int d0   = (colbase + col4) & 63;
    const float* alp = al + ((m * H_ + head) * D_ + d0);
    const float* arp = ar + ((m * H_ + head) * D_ + d0);
    float4 av = *(const float4*)alp;
    float4 rv = *(const float4*)arp;
    float vl[4], vr[4];
#pragma unroll
    for (int i = 0; i < 4; i++) {
        vl[i] = acc[i][0] * av.x + acc[i][1] * av.y + acc[i][2] * av.z + acc[i][3] * av.w;
        vr[i] = acc[i][0] * rv.x + acc[i][1] * rv.y + acc[i][2] * rv.z + acc[i][3] * rv.w;
    }
    for (int off = 8; off; off >>= 1) {
#pragma unroll
        for (int i = 0; i < 4; i++) {
            vl[i] += __shfl_down(vl[i], off, 16);
            vr[i] += __shfl_down(vr[i], off, 16);
        }
    }
    if ((tx & 15) == 0) {
#pragma unroll
        for (int i = 0; i < 4; i++) {
            int o = (m * N_ + rowbase + row4 + i) * H_ + head;
            el[o] = vl[i];
            er[o] = vr[i];
        }
    }
}

// K2: in-degree histogram over (m, dst)
__global__ __launch_bounds__(256) void hist_kernel(const int* __restrict__ dst,
                                                   int* __restrict__ cnt) {
    int i = blockIdx.x * 256 + threadIdx.x;
    if (i >= ME_) return;
    int m = i / E_;
    atomicAdd(&cnt[m * N_ + dst[i]], 1);
}

// K3: single-block exclusive scan over cnt[MN] -> rowstart[MN+1], cursor[MN]
__global__ __launch_bounds__(1024) void scan_kernel(const int* __restrict__ cnt,
                                                    int* __restrict__ rowstart,
                                                    int* __restrict__ cursor) {
    __shared__ int lds[1024];
    const int t  = threadIdx.x;
    const int CH = (MN_ + 1023) / 1024;            // 59
    const int b  = t * CH;
    const int e  = min(b + CH, MN_);
    int sum = 0;
    for (int i = b; i < e; i++) sum += cnt[i];
    lds[t] = sum;
    for (int s = 1; s < 1024; s <<= 1) {
        __syncthreads();
        int v = (t >= s) ? lds[t - s] : 0;
        __syncthreads();
        lds[t] += v;
    }
    __syncthreads();
    int run = lds[t] - sum;                        // exclusive prefix of this chunk
    for (int i = b; i < e; i++) {
        rowstart[i] = run;
        cursor[i]   = run;
        run += cnt[i];
    }
    if (t == 1023) rowstart[MN_] = lds[1023];
}

// K4: scatter edge src ids into CSR order
__global__ __launch_bounds__(256) void scatter_kernel(const int* __restrict__ src,
                                                      const int* __restrict__ dst,
                                                      int* __restrict__ cursor,
                                                      int* __restrict__ esrc) {
    int i = blockIdx.x * 256 + threadIdx.x;
    if (i >= ME_) return;
    int m = i / E_;
    int pos = atomicAdd(&cursor[m * N_ + dst[i]], 1);
    esrc[pos] = src[i];
}

// K5: wave per (m, dst): single-pass softmax-weighted aggregation.
//   z = (sum_j ee_j * feat[src_j]) / (sum_j ee_j) + bias      (ee recomputed on the fly)
__global__ __launch_bounds__(256) void aggregate_csr(
    const int* __restrict__ rowstart, const int* __restrict__ esrc,
    const float* __restrict__ el, const float* __restrict__ er,
    const ushort* __restrict__ feat, const float* __restrict__ bias,
    float* __restrict__ z) {
    const int g = blockIdx.x * 4 + (threadIdx.x >> 6);   // m*N + n, grid covers exactly MN_
    const int lane = threadIdx.x & 63;
    const int m = g / N_;
    const int head = lane >> 4;
    const int beg = rowstart[g], end = rowstart[g + 1];
    const float erv = er[(size_t)g * H_ + head];         // wave-constant per head group
    const int mN = m * N_;
    const ushort* fm = feat + (size_t)mN * HD_;
    float a0 = 0.f, a1 = 0.f, a2 = 0.f, a3 = 0.f, den = 0.f;
    for (int j = beg; j < end; j++) {
        int s = esrc[j];
        float x = el[(size_t)(mN + s) * H_ + head] + erv;
        x = x > 0.f ? x : NEG_SLOPE * x;
        float ee = __expf(x);
        ushort4 f4 = *(const ushort4*)&fm[(size_t)s * HD_ + 4 * lane];
        a0 += ee * bf2f(f4.x);
        a1 += ee * bf2f(f4.y);
        a2 += ee * bf2f(f4.z);
        a3 += ee * bf2f(f4.w);
        den += ee;
    }
    float inv = 1.f / fmaxf(den, 1e-9f);
    float4 b4 = *(const float4*)&bias[m * HD_ + 4 * lane];
    float4 o;
    o.x = a0 * inv + b4.x;
    o.y = a1 * inv + b4.y;
    o.z = a2 * inv + b4.z;
    o.w = a3 * inv + b4.w;
    *(float4*)&z[(size_t)g * HD_ + 4 * lane] = o;
}

// K6: tiled GEMM semantic attention.
constexpr int SR_ = 32;   // rows per block
constexpr int SK_ = 32;   // K chunk
__global__ __launch_bounds__(256) void semantic_w(
    const float* __restrict__ z, const float* __restrict__ W1,
    const float* __restrict__ b1, const float* __restrict__ W2,
    float* __restrict__ wsum) {
    const int tx = threadIdx.x;
    const int rowbase = blockIdx.x * SR_;           // global row (m*N+n)
    const int m = rowbase / N_;
    const int col4 = (tx & 31) * 4;                 // cols col4..col4+3
    const int row4 = (tx >> 5) * 4;                 // rows row4..row4+3 (local)

    __shared__ float zs[SK_][SR_ + 4];              // transposed z tile
    __shared__ float w1s[SK_][HID_];                // W1 tile
    __shared__ float red[4];

    float acc[4][4];
#pragma unroll
    for (int i = 0; i < 4; i++)
#pragma unroll
        for (int j = 0; j < 4; j++) acc[i][j] = 0.f;

    const int lr = tx >> 3;                         // load row 0..31
    const int lk = (tx & 7) * 4;                    // load k offset 0,4,..28

    for (int k0 = 0; k0 < HD_; k0 += SK_) {
        float4 zv = *(const float4*)&z[((size_t)(rowbase + lr)) * HD_ + k0 + lk];
        zs[lk + 0][lr] = zv.x;
        zs[lk + 1][lr] = zv.y;
        zs[lk + 2][lr] = zv.z;
        zs[lk + 3][lr] = zv.w;
#pragma unroll
        for (int i = 0; i < 4; i++) {
            int idx = (tx + i * 256) * 4;           // float index 0..16380
            *(float4*)&w1s[0][idx] = *(const float4*)&W1[(size_t)k0 * HID_ + idx];
        }
        __syncthreads();
#pragma unroll
        for (int k = 0; k < SK_; k++) {
            float4 za = *(const float4*)&zs[k][row4];
            float4 wa = *(const float4*)&w1s[k][col4];
            acc[0][0] += za.x * wa.x; acc[0][1] += za.x * wa.y; acc[0][2] += za.x * wa.z; acc[0][3] += za.x * wa.w;
            acc[1][0] += za.y * wa.x; acc[1][1] += za.y * wa.y; acc[1][2] += za.y * wa.z; acc[1][3] += za.y * wa.w;
            acc[2][0] += za.z * wa.x; acc[2][1] += za.z * wa.y; acc[2][2] += za.z * wa.z; acc[2][3] += za.z * wa.w;
            acc[3][0] += za.w * wa.x; acc[3][1] += za.w * wa.y; acc[3][2] += za.w * wa.z; acc[3][3] += za.w * wa.w;
        }
        __syncthreads();
    }

    float4 bb = *(const float4*)&b1[col4];
    float4 w2 = *(const float4*)&W2[col4];
    float local = 0.f;
#pragma unroll
    for (int i = 0; i < 4; i++) {
        local += tanhf(acc[i][0] + bb.x) * w2.x;
        local += tanhf(acc[i][1] + bb.y) * w2.y;
        local += tanhf(acc[i][2] + bb.z) * w2.z;
        local += tanhf(acc[i][3] + bb.w) * w2.w;
    }
    for (int off = 32; off; off >>= 1) local += __shfl_down(local, off);
    if ((tx & 63) == 0) red[tx >> 6] = local;
    __syncthreads();
    if (tx == 0) atomicAdd(&wsum[m], red[0] + red[1] + red[2] + red[3]);
}

// K7: beta = softmax(wsum / N)
__global__ void beta_kernel(const float* __restrict__ wsum, float* __restrict__ beta) {
    if (threadIdx.x == 0 && blockIdx.x == 0) {
        float w0 = wsum[0] / (float)N_, w1 = wsum[1] / (float)N_, w2 = wsum[2] / (float)N_;
        float mx = fmaxf(w0, fmaxf(w1, w2));
        float e0 = __expf(w0 - mx), e1 = __expf(w1 - mx), e2 = __expf(w2 - mx);
        float s = e0 + e1 + e2;
        beta[0] = e0 / s; beta[1] = e1 / s; beta[2] = e2 / s;
    }
}

// K8: out[n][c] = sum_m beta[m] * z[m][n][c], fp32 store
__global__ __launch_bounds__(256) void final_out(
    const float* __restrict__ z, const float* __restrict__ beta,
    float* __restrict__ out) {
    int idx = blockIdx.x * 256 + threadIdx.x;       // float4 index over [N*HD/4]
    if (idx >= N_ * HD_ / 4) return;
    float b0 = beta[0], b1 = beta[1], b2 = beta[2];
    float4 z0 = *(const float4*)&z[(size_t)idx * 4];
    float4 z1 = *(const float4*)&z[(size_t)N_ * HD_ + (size_t)idx * 4];
    float4 z2 = *(const float4*)&z[(size_t)2 * N_ * HD_ + (size_t)idx * 4];
    float4 o;
    o.x = b0 * z0.x + b1 * z1.x + b2 * z2.x;
    o.y = b0 * z0.y + b1 * z1.y + b2 * z2.y;
    o.z = b0 * z0.z + b1 * z1.z + b2 * z2.z;
    o.w = b0 * z0.w + b1 * z1.w + b2 * z2.w;
    *(float4*)&out[(size_t)idx * 4] = o;
}

extern "C" void kernel_launch(void* const* d_in, const int* in_sizes, int n_in,
                              void* d_out, int out_size, void* d_ws, size_t ws_size,
                              hipStream_t stream) {
    const float* h    = (const float*)d_in[0];
    const int*   src  = (const int*)d_in[1];
    const int*   dst  = (const int*)d_in[2];
    const float* W    = (const float*)d_in[3];
    const float* al   = (const float*)d_in[4];
    const float* ar   = (const float*)d_in[5];
    const float* bias = (const float*)d_in[6];
    const float* W1   = (const float*)d_in[7];
    const float* b1   = (const float*)d_in[8];
    const float* W2   = (const float*)d_in[9];

    char* ws = (char*)d_ws;
    ushort* feat     = (ushort*)(ws + FEAT_OFF);
    float*  z        = (float*)(ws + Z_OFF);
    float*  el       = (float*)(ws + EL_OFF);
    float*  er       = (float*)(ws + ER_OFF);
    int*    esrc     = (int*)(ws + ESRC_OFF);
    int*    rowstart = (int*)(ws + ROW_OFF);
    int*    cursor   = (int*)(ws + CUR_OFF);
    int*    cnt      = (int*)(ws + CNT_OFF);
    float*  wsum     = (float*)(ws + WSUM_OFF);
    float*  beta     = (float*)(ws + BETA_OFF);

    // zero cnt + wsum (contiguous)
    hipMemsetAsync(ws + CNT_OFF, 0, 240000 + 64, stream);

    feat_gemm<<<dim3(N_ / 32, 2 * M_), 256, 0, stream>>>(h, W, al, ar, feat, el, er);
    hist_kernel<<<(ME_ + 255) / 256, 256, 0, stream>>>(dst, cnt);
    scan_kernel<<<1, 1024, 0, stream>>>(cnt, rowstart, cursor);
    scatter_kernel<<<(ME_ + 255) / 256, 256, 0, stream>>>(src, dst, cursor, esrc);
    aggregate_csr<<<MN_ / 4, 256, 0, stream>>>(rowstart, esrc, el, er, feat, bias, z);
    semantic_w<<<MN_ / SR_, 256, 0, stream>>>(z, W1, b1, W2, wsum);
    beta_kernel<<<1, 64, 0, stream>>>(wsum, beta);
    final_out<<<N_ * HD_ / 4 / 256, 256, 0, stream>>>(z, beta, (float*)d_out);
}

// Round 6
// 393.797 us; speedup vs baseline: 11.4106x; 1.3983x over previous
//
#include <hip/hip_runtime.h>
#include <hip/hip_bf16.h>

// Problem constants
constexpr int N_   = 20000;
constexpr int E_   = 320000;
constexpr int M_   = 3;
constexpr int KIN  = 128;   // in_size
constexpr int H_   = 4;     // heads
constexpr int D_   = 64;    // per-head dim
constexpr int HD_  = 256;   // H*D
constexpr int HID_ = 128;   // semantic hidden
constexpr int MN_  = M_ * N_;   // 60000 segments
constexpr int ME_  = M_ * E_;   // 960000 edges
constexpr int NB_  = (MN_ + 255) / 256;  // 235 scan blocks
#define NEG_SLOPE 0.2f

// Workspace layout (bytes) — ~98.6 MB
constexpr size_t FEAT_OFF = 0;           // ushort[M*N*HD]  = 30,720,000 (internal bf16 feat)
constexpr size_t Z_OFF    = 30720000;    // float [M*N*HD]  = 61,440,000
constexpr size_t EL_OFF   = 92160000;    // float [M*N*H]   =    960,000
constexpr size_t ER_OFF   = 93120000;    // float [M*N*H]   =    960,000
constexpr size_t ESRC_OFF = 94080000;    // int   [M*E]     =  3,840,000 (CSR-ordered src ids)
constexpr size_t ROW_OFF  = 97920000;    // int   [MN+1]    =    240,064 (padded)
constexpr size_t CUR_OFF  = 98160064;    // int   [MN]      =    240,000 (scatter cursors)
constexpr size_t CNT_OFF  = 98400064;    // int   [MN]      =    240,000 (histogram)  } memset
constexpr size_t WSUM_OFF = 98640064;    // float [16]                               } together
constexpr size_t BS_OFF   = 98640128;    // int   [256]  per-block sums
constexpr size_t BO_OFF   = 98641152;    // int   [256]  per-block offsets

__device__ __forceinline__ float bf2f(ushort u) {
    union { unsigned int i; float f; } v; v.i = ((unsigned int)u) << 16; return v.f;
}
__device__ __forceinline__ ushort f2bf(float f) {
    union { float f; unsigned int i; } v; v.f = f;
    unsigned int i = v.i;
    unsigned int r = (i + 0x7fffu + ((i >> 16) & 1u)) >> 16;   // RNE
    return (ushort)r;
}

// K1: feat = h @ W[m] (bf16 store) + fused el/er epilogue — register-tiled GEMM.
__global__ __launch_bounds__(256) void feat_gemm(
    const float* __restrict__ h, const float* __restrict__ W,
    const float* __restrict__ al, const float* __restrict__ ar,
    ushort* __restrict__ feat, float* __restrict__ el, float* __restrict__ er) {
    const int tx      = threadIdx.x;
    const int rowbase = blockIdx.x * 32;            // node base
    const int m       = blockIdx.y >> 1;
    const int colbase = (blockIdx.y & 1) * 128;
    const int col4    = (tx & 31) * 4;              // col within 128-tile
    const int row4    = (tx >> 5) * 4;              // local row

    __shared__ float hs[32][36];                    // transposed h tile [k][row], +4 pad
    __shared__ float ws_[32][128];                  // W tile [k][col]

    float acc[4][4];
#pragma unroll
    for (int i = 0; i < 4; i++)
#pragma unroll
        for (int j = 0; j < 4; j++) acc[i][j] = 0.f;

    const int lr = tx >> 3;                         // load row 0..31
    const int lk = (tx & 7) * 4;                    // load k offset 0,4,..28

    for (int k0 = 0; k0 < KIN; k0 += 32) {
        float4 hv = *(const float4*)&h[(size_t)(rowbase + lr) * KIN + k0 + lk];
        hs[lk + 0][lr] = hv.x;
        hs[lk + 1][lr] = hv.y;
        hs[lk + 2][lr] = hv.z;
        hs[lk + 3][lr] = hv.w;
#pragma unroll
        for (int i = 0; i < 4; i++) {
            int idx = (tx + i * 256) * 4;           // float index 0..4092 in 32x128 tile
            int kk  = idx >> 7, cc = idx & 127;
            *(float4*)&ws_[kk][cc] =
                *(const float4*)&W[(size_t)m * KIN * HD_ + (size_t)(k0 + kk) * HD_ + colbase + cc];
        }
        __syncthreads();
#pragma unroll
        for (int k = 0; k < 32; k++) {
            float4 za = *(const float4*)&hs[k][row4];
            float4 wa = *(const float4*)&ws_[k][col4];
            acc[0][0] += za.x * wa.x; acc[0][1] += za.x * wa.y; acc[0][2] += za.x * wa.z; acc[0][3] += za.x * wa.w;
            acc[1][0] += za.y * wa.x; acc[1][1] += za.y * wa.y; acc[1][2] += za.y * wa.z; acc[1][3] += za.y * wa.w;
            acc[2][0] += za.z * wa.x; acc[2][1] += za.z * wa.y; acc[2][2] += za.z * wa.z; acc[2][3] += za.z * wa.w;
            acc[3][0] += za.w * wa.x; acc[3][1] += za.w * wa.y; acc[3][2] += za.w * wa.z; acc[3][3] += za.w * wa.w;
        }
        __syncthreads();
    }

#pragma unroll
    for (int i = 0; i < 4; i++) {
        size_t fo = ((size_t)m * N_ + rowbase + row4 + i) * HD_ + colbase + col4;
        ushort4 f4;
        f4.x = f2bf(acc[i][0]); f4.y = f2bf(acc[i][1]);
        f4.z = f2bf(acc[i][2]); f4.w = f2bf(acc[i][3]);
        *(ushort4*)&feat[fo] = f4;
    }

    const int head = (colbase + col4) >> 6;
    const int d0   = (colbase + col4) & 63;
    const float* alp = al + ((m * H_ + head) * D_ + d0);
    const float* arp = ar + ((m * H_ + head) * D_ + d0);
    float4 av = *(const float4*)alp;
    float4 rv = *(const float4*)arp;
    float vl[4], vr[4];
#pragma unroll
    for (int i = 0; i < 4; i++) {
        vl[i] = acc[i][0] * av.x + acc[i][1] * av.y + acc[i][2] * av.z + acc[i][3] * av.w;
        vr[i] = acc[i][0] * rv.x + acc[i][1] * rv.y + acc[i][2] * rv.z + acc[i][3] * rv.w;
    }
    for (int off = 8; off; off >>= 1) {
#pragma unroll
        for (int i = 0; i < 4; i++) {
            vl[i] += __shfl_down(vl[i], off, 16);
            vr[i] += __shfl_down(vr[i], off, 16);
        }
    }
    if ((tx & 15) == 0) {
#pragma unroll
        for (int i = 0; i < 4; i++) {
            int o = (m * N_ + rowbase + row4 + i) * H_ + head;
            el[o] = vl[i];
            er[o] = vr[i];
        }
    }
}

// K2: in-degree histogram over (m, dst)
__global__ __launch_bounds__(256) void hist_kernel(const int* __restrict__ dst,
                                                   int* __restrict__ cnt) {
    int i = blockIdx.x * 256 + threadIdx.x;
    if (i >= ME_) return;
    int m = i / E_;
    atomicAdd(&cnt[m * N_ + dst[i]], 1);
}

// K3a: per-block scan. Block b: coalesced load cnt[b*256+t], in-block exclusive
// scan -> rowstart (pre-offset), block total -> blocksum[b].
__global__ __launch_bounds__(256) void scan_phase1(const int* __restrict__ cnt,
                                                   int* __restrict__ rowstart,
                                                   int* __restrict__ blocksum) {
    __shared__ int lds[256];
    const int t = threadIdx.x;
    const int i = blockIdx.x * 256 + t;
    int v = (i < MN_) ? cnt[i] : 0;
    lds[t] = v;
    for (int s = 1; s < 256; s <<= 1) {
        __syncthreads();
        int tmp = (t >= s) ? lds[t - s] : 0;
        __syncthreads();
        lds[t] += tmp;
    }
    __syncthreads();
    if (i < MN_) rowstart[i] = lds[t] - v;          // exclusive, pre-offset
    if (t == 255) blocksum[blockIdx.x] = lds[255];
}

// K3b: single small block scans NB_ block sums -> exclusive blockoff
__global__ __launch_bounds__(256) void scan_phase2(const int* __restrict__ blocksum,
                                                   int* __restrict__ blockoff) {
    __shared__ int lds[256];
    const int t = threadIdx.x;
    int v = (t < NB_) ? blocksum[t] : 0;
    lds[t] = v;
    for (int s = 1; s < 256; s <<= 1) {
        __syncthreads();
        int tmp = (t >= s) ? lds[t - s] : 0;
        __syncthreads();
        lds[t] += tmp;
    }
    __syncthreads();
    if (t < NB_) blockoff[t] = lds[t] - v;
}

// K3c: add block offsets; emit final rowstart + cursor
__global__ __launch_bounds__(256) void scan_phase3(int* __restrict__ rowstart,
                                                   const int* __restrict__ blockoff,
                                                   int* __restrict__ cursor) {
    const int i = blockIdx.x * 256 + threadIdx.x;
    if (i < MN_) {
        int v = rowstart[i] + blockoff[i >> 8];
        rowstart[i] = v;
        cursor[i]   = v;
    }
    if (i == 0) rowstart[MN_] = ME_;               // total is compile-time constant
}

// K4: scatter edge src ids into CSR order
__global__ __launch_bounds__(256) void scatter_kernel(const int* __restrict__ src,
                                                      const int* __restrict__ dst,
                                                      int* __restrict__ cursor,
                                                      int* __restrict__ esrc) {
    int i = blockIdx.x * 256 + threadIdx.x;
    if (i >= ME_) return;
    int m = i / E_;
    int pos = atomicAdd(&cursor[m * N_ + dst[i]], 1);
    esrc[pos] = src[i];
}

// K5: wave per (m, dst): single-pass softmax-weighted aggregation, 4-wide unroll
// for memory-level parallelism on the esrc -> el/feat dependent-load chain.
__global__ __launch_bounds__(256) void aggregate_csr(
    const int* __restrict__ rowstart, const int* __restrict__ esrc,
    const float* __restrict__ el, const float* __restrict__ er,
    const ushort* __restrict__ feat, const float* __restrict__ bias,
    float* __restrict__ z) {
    const int g = blockIdx.x * 4 + (threadIdx.x >> 6);   // m*N + n
    const int lane = threadIdx.x & 63;
    const int m = g / N_;
    const int head = lane >> 4;
    const int beg = rowstart[g], end = rowstart[g + 1];
    const float erv = er[(size_t)g * H_ + head];
    const int mN = m * N_;
    const ushort* fm = feat + (size_t)mN * HD_;
    float a0 = 0.f, a1 = 0.f, a2 = 0.f, a3 = 0.f, den = 0.f;

    int j = beg;
    for (; j + 4 <= end; j += 4) {
        int s0 = esrc[j], s1 = esrc[j + 1], s2 = esrc[j + 2], s3 = esrc[j + 3];
        float x0 = el[(size_t)(mN + s0) * H_ + head] + erv;
        float x1 = el[(size_t)(mN + s1) * H_ + head] + erv;
        float x2 = el[(size_t)(mN + s2) * H_ + head] + erv;
        float x3 = el[(size_t)(mN + s3) * H_ + head] + erv;
        ushort4 f0 = *(const ushort4*)&fm[(size_t)s0 * HD_ + 4 * lane];
        ushort4 f1 = *(const ushort4*)&fm[(size_t)s1 * HD_ + 4 * lane];
        ushort4 f2 = *(const ushort4*)&fm[(size_t)s2 * HD_ + 4 * lane];
        ushort4 f3 = *(const ushort4*)&fm[(size_t)s3 * HD_ + 4 * lane];
        x0 = x0 > 0.f ? x0 : NEG_SLOPE * x0;
        x1 = x1 > 0.f ? x1 : NEG_SLOPE * x1;
        x2 = x2 > 0.f ? x2 : NEG_SLOPE * x2;
        x3 = x3 > 0.f ? x3 : NEG_SLOPE * x3;
        float e0 = __expf(x0), e1 = __expf(x1), e2 = __expf(x2), e3 = __expf(x3);
        a0 += e0 * bf2f(f0.x) + e1 * bf2f(f1.x) + e2 * bf2f(f2.x) + e3 * bf2f(f3.x);
        a1 += e0 * bf2f(f0.y) + e1 * bf2f(f1.y) + e2 * bf2f(f2.y) + e3 * bf2f(f3.y);
        a2 += e0 * bf2f(f0.z) + e1 * bf2f(f1.z) + e2 * bf2f(f2.z) + e3 * bf2f(f3.z);
        a3 += e0 * bf2f(f0.w) + e1 * bf2f(f1.w) + e2 * bf2f(f2.w) + e3 * bf2f(f3.w);
        den += e0 + e1 + e2 + e3;
    }
    for (; j < end; j++) {
        int s = esrc[j];
        float x = el[(size_t)(mN + s) * H_ + head] + erv;
        x = x > 0.f ? x : NEG_SLOPE * x;
        float ee = __expf(x);
        ushort4 f4 = *(const ushort4*)&fm[(size_t)s * HD_ + 4 * lane];
        a0 += ee * bf2f(f4.x);
        a1 += ee * bf2f(f4.y);
        a2 += ee * bf2f(f4.z);
        a3 += ee * bf2f(f4.w);
        den += ee;
    }
    float inv = 1.f / fmaxf(den, 1e-9f);
    float4 b4 = *(const float4*)&bias[m * HD_ + 4 * lane];
    float4 o;
    o.x = a0 * inv + b4.x;
    o.y = a1 * inv + b4.y;
    o.z = a2 * inv + b4.z;
    o.w = a3 * inv + b4.w;
    *(float4*)&z[(size_t)g * HD_ + 4 * lane] = o;
}

// K6: tiled GEMM semantic attention.
constexpr int SR_ = 32;   // rows per block
constexpr int SK_ = 32;   // K chunk
__global__ __launch_bounds__(256) void semantic_w(
    const float* __restrict__ z, const float* __restrict__ W1,
    const float* __restrict__ b1, const float* __restrict__ W2,
    float* __restrict__ wsum) {
    const int tx = threadIdx.x;
    const int rowbase = blockIdx.x * SR_;           // global row (m*N+n)
    const int m = rowbase / N_;
    const int col4 = (tx & 31) * 4;                 // cols col4..col4+3
    const int row4 = (tx >> 5) * 4;                 // rows row4..row4+3 (local)

    __shared__ float zs[SK_][SR_ + 4];              // transposed z tile
    __shared__ float w1s[SK_][HID_];                // W1 tile
    __shared__ float red[4];

    float acc[4][4];
#pragma unroll
    for (int i = 0; i < 4; i++)
#pragma unroll
        for (int j = 0; j < 4; j++) acc[i][j] = 0.f;

    const int lr = tx >> 3;                         // load row 0..31
    const int lk = (tx & 7) * 4;                    // load k offset 0,4,..28

    for (int k0 = 0; k0 < HD_; k0 += SK_) {
        float4 zv = *(const float4*)&z[((size_t)(rowbase + lr)) * HD_ + k0 + lk];
        zs[lk + 0][lr] = zv.x;
        zs[lk + 1][lr] = zv.y;
        zs[lk + 2][lr] = zv.z;
        zs[lk + 3][lr] = zv.w;
#pragma unroll
        for (int i = 0; i < 4; i++) {
            int idx = (tx + i * 256) * 4;           // float index 0..16380
            *(float4*)&w1s[0][idx] = *(const float4*)&W1[(size_t)k0 * HID_ + idx];
        }
        __syncthreads();
#pragma unroll
        for (int k = 0; k < SK_; k++) {
            float4 za = *(const float4*)&zs[k][row4];
            float4 wa = *(const float4*)&w1s[k][col4];
            acc[0][0] += za.x * wa.x; acc[0][1] += za.x * wa.y; acc[0][2] += za.x * wa.z; acc[0][3] += za.x * wa.w;
            acc[1][0] += za.y * wa.x; acc[1][1] += za.y * wa.y; acc[1][2] += za.y * wa.z; acc[1][3] += za.y * wa.w;
            acc[2][0] += za.z * wa.x; acc[2][1] += za.z * wa.y; acc[2][2] += za.z * wa.z; acc[2][3] += za.z * wa.w;
            acc[3][0] += za.w * wa.x; acc[3][1] += za.w * wa.y; acc[3][2] += za.w * wa.z; acc[3][3] += za.w * wa.w;
        }
        __syncthreads();
    }

    float4 bb = *(const float4*)&b1[col4];
    float4 w2 = *(const float4*)&W2[col4];
    float local = 0.f;
#pragma unroll
    for (int i = 0; i < 4; i++) {
        local += tanhf(acc[i][0] + bb.x) * w2.x;
        local += tanhf(acc[i][1] + bb.y) * w2.y;
        local += tanhf(acc[i][2] + bb.z) * w2.z;
        local += tanhf(acc[i][3] + bb.w) * w2.w;
    }
    for (int off = 32; off; off >>= 1) local += __shfl_down(local, off);
    if ((tx & 63) == 0) red[tx >> 6] = local;
    __syncthreads();
    if (tx == 0) atomicAdd(&wsum[m], red[0] + red[1] + red[2] + red[3]);
}

// K7: out[n][c] = sum_m beta[m] * z[m][n][c]; beta computed inline from wsum.
__global__ __launch_bounds__(256) void final_out(
    const float* __restrict__ z, const float* __restrict__ wsum,
    float* __restrict__ out) {
    int idx = blockIdx.x * 256 + threadIdx.x;       // float4 index over [N*HD/4]
    if (idx >= N_ * HD_ / 4) return;
    float w0 = wsum[0], w1 = wsum[1], w2 = wsum[2];
    float mx = fmaxf(w0, fmaxf(w1, w2));
    float e0 = __expf((w0 - mx) / (float)N_ * 1.0f), e1, e2;
    // note: softmax over wsum/N; divide before exp
    e0 = __expf((w0 - mx) / (float)N_);
    e1 = __expf((w1 - mx) / (float)N_);
    e2 = __expf((w2 - mx) / (float)N_);
    float sinv = 1.f / (e0 + e1 + e2);
    float b0 = e0 * sinv, b1 = e1 * sinv, b2 = e2 * sinv;
    float4 z0 = *(const float4*)&z[(size_t)idx * 4];
    float4 z1 = *(const float4*)&z[(size_t)N_ * HD_ + (size_t)idx * 4];
    float4 z2 = *(const float4*)&z[(size_t)2 * N_ * HD_ + (size_t)idx * 4];
    float4 o;
    o.x = b0 * z0.x + b1 * z1.x + b2 * z2.x;
    o.y = b0 * z0.y + b1 * z1.y + b2 * z2.y;
    o.z = b0 * z0.z + b1 * z1.z + b2 * z2.z;
    o.w = b0 * z0.w + b1 * z1.w + b2 * z2.w;
    *(float4*)&out[(size_t)idx * 4] = o;
}

extern "C" void kernel_launch(void* const* d_in, const int* in_sizes, int n_in,
                              void* d_out, int out_size, void* d_ws, size_t ws_size,
                              hipStream_t stream) {
    const float* h    = (const float*)d_in[0];
    const int*   src  = (const int*)d_in[1];
    const int*   dst  = (const int*)d_in[2];
    const float* W    = (const float*)d_in[3];
    const float* al   = (const float*)d_in[4];
    const float* ar   = (const float*)d_in[5];
    const float* bias = (const float*)d_in[6];
    const float* W1   = (const float*)d_in[7];
    const float* b1   = (const float*)d_in[8];
    const float* W2   = (const float*)d_in[9];

    char* ws = (char*)d_ws;
    ushort* feat     = (ushort*)(ws + FEAT_OFF);
    float*  z        = (float*)(ws + Z_OFF);
    float*  el       = (float*)(ws + EL_OFF);
    float*  er       = (float*)(ws + ER_OFF);
    int*    esrc     = (int*)(ws + ESRC_OFF);
    int*    rowstart = (int*)(ws + ROW_OFF);
    int*    cursor   = (int*)(ws + CUR_OFF);
    int*    cnt      = (int*)(ws + CNT_OFF);
    float*  wsum     = (float*)(ws + WSUM_OFF);
    int*    blocksum = (int*)(ws + BS_OFF);
    int*    blockoff = (int*)(ws + BO_OFF);

    // zero cnt + wsum (contiguous)
    hipMemsetAsync(ws + CNT_OFF, 0, 240000 + 64, stream);

    feat_gemm<<<dim3(N_ / 32, 2 * M_), 256, 0, stream>>>(h, W, al, ar, feat, el, er);
    hist_kernel<<<(ME_ + 255) / 256, 256, 0, stream>>>(dst, cnt);
    scan_phase1<<<NB_, 256, 0, stream>>>(cnt, rowstart, blocksum);
    scan_phase2<<<1, 256, 0, stream>>>(blocksum, blockoff);
    scan_phase3<<<NB_, 256, 0, stream>>>(rowstart, blockoff, cursor);
    scatter_kernel<<<(ME_ + 255) / 256, 256, 0, stream>>>(src, dst, cursor, esrc);
    aggregate_csr<<<MN_ / 4, 256, 0, stream>>>(rowstart, esrc, el, er, feat, bias, z);
    semantic_w<<<MN_ / SR_, 256, 0, stream>>>(z, W1, b1, W2, wsum);
    final_out<<<N_ * HD_ / 4 / 256, 256, 0, stream>>>(z, wsum, (float*)d_out);
}

// Round 7
// 379.092 us; speedup vs baseline: 11.8532x; 1.0388x over previous
//
#include <hip/hip_runtime.h>
#include <hip/hip_bf16.h>

// Problem constants
constexpr int N_   = 20000;
constexpr int E_   = 320000;
constexpr int M_   = 3;
constexpr int KIN  = 128;   // in_size
constexpr int H_   = 4;     // heads
constexpr int D_   = 64;    // per-head dim
constexpr int HD_  = 256;   // H*D
constexpr int HID_ = 128;   // semantic hidden
constexpr int MN_  = M_ * N_;   // 60000 segments
constexpr int ME_  = M_ * E_;   // 960000 edges
constexpr int NB_  = (MN_ + 255) / 256;  // 235 scan blocks
#define NEG_SLOPE 0.2f

// Workspace layout (bytes) — ~98.7 MB
constexpr size_t FEAT_OFF = 0;           // ushort[M*N*HD]  = 30,720,000 (internal bf16 feat)
constexpr size_t Z_OFF    = 30720000;    // float [M*N*HD]  = 61,440,000
constexpr size_t EL_OFF   = 92160000;    // float [M*N*H]   =    960,000
constexpr size_t ER_OFF   = 93120000;    // float [M*N*H]   =    960,000
constexpr size_t ESRC_OFF = 94080000;    // int   [M*E]     =  3,840,000 (CSR-ordered src ids)
constexpr size_t ROW_OFF  = 97920000;    // int   [MN+1]    =    240,064 (padded)
constexpr size_t CUR_OFF  = 98160064;    // int   [MN]      =    240,000 (scatter cursors)
constexpr size_t CNT_OFF  = 98400064;    // int   [MN]      =    240,000 (histogram)  } memset
constexpr size_t WSUM_OFF = 98640064;    // float [16]                               } together
constexpr size_t BS_OFF   = 98640128;    // int   [256]  per-block sums
constexpr size_t BO_OFF   = 98641152;    // int   [256]  per-block offsets
constexpr size_t W1T_OFF  = 98642176;    // ushort[HID*HD] = 65,536 (bf16 W1 transposed)

typedef __attribute__((ext_vector_type(8))) short short8;   // 8 bf16 (4 VGPRs)
typedef __attribute__((ext_vector_type(4))) float f32x4;    // MFMA accumulator

__device__ __forceinline__ float bf2f(ushort u) {
    union { unsigned int i; float f; } v; v.i = ((unsigned int)u) << 16; return v.f;
}
__device__ __forceinline__ ushort f2bf(float f) {
    union { float f; unsigned int i; } v; v.f = f;
    unsigned int i = v.i;
    unsigned int r = (i + 0x7fffu + ((i >> 16) & 1u)) >> 16;   // RNE
    return (ushort)r;
}

// K1: feat = h @ W[m] (bf16 store) + fused el/er epilogue — register-tiled GEMM.
__global__ __launch_bounds__(256) void feat_gemm(
    const float* __restrict__ h, const float* __restrict__ W,
    const float* __restrict__ al, const float* __restrict__ ar,
    ushort* __restrict__ feat, float* __restrict__ el, float* __restrict__ er) {
    const int tx      = threadIdx.x;
    const int rowbase = blockIdx.x * 32;            // node base
    const int m       = blockIdx.y >> 1;
    const int colbase = (blockIdx.y & 1) * 128;
    const int col4    = (tx & 31) * 4;              // col within 128-tile
    const int row4    = (tx >> 5) * 4;              // local row

    __shared__ float hs[32][36];                    // transposed h tile [k][row], +4 pad
    __shared__ float ws_[32][128];                  // W tile [k][col]

    float acc[4][4];
#pragma unroll
    for (int i = 0; i < 4; i++)
#pragma unroll
        for (int j = 0; j < 4; j++) acc[i][j] = 0.f;

    const int lr = tx >> 3;                         // load row 0..31
    const int lk = (tx & 7) * 4;                    // load k offset 0,4,..28

    for (int k0 = 0; k0 < KIN; k0 += 32) {
        float4 hv = *(const float4*)&h[(size_t)(rowbase + lr) * KIN + k0 + lk];
        hs[lk + 0][lr] = hv.x;
        hs[lk + 1][lr] = hv.y;
        hs[lk + 2][lr] = hv.z;
        hs[lk + 3][lr] = hv.w;
#pragma unroll
        for (int i = 0; i < 4; i++) {
            int idx = (tx + i * 256) * 4;           // float index 0..4092 in 32x128 tile
            int kk  = idx >> 7, cc = idx & 127;
            *(float4*)&ws_[kk][cc] =
                *(const float4*)&W[(size_t)m * KIN * HD_ + (size_t)(k0 + kk) * HD_ + colbase + cc];
        }
        __syncthreads();
#pragma unroll
        for (int k = 0; k < 32; k++) {
            float4 za = *(const float4*)&hs[k][row4];
            float4 wa = *(const float4*)&ws_[k][col4];
            acc[0][0] += za.x * wa.x; acc[0][1] += za.x * wa.y; acc[0][2] += za.x * wa.z; acc[0][3] += za.x * wa.w;
            acc[1][0] += za.y * wa.x; acc[1][1] += za.y * wa.y; acc[1][2] += za.y * wa.z; acc[1][3] += za.y * wa.w;
            acc[2][0] += za.z * wa.x; acc[2][1] += za.z * wa.y; acc[2][2] += za.z * wa.z; acc[2][3] += za.z * wa.w;
            acc[3][0] += za.w * wa.x; acc[3][1] += za.w * wa.y; acc[3][2] += za.w * wa.z; acc[3][3] += za.w * wa.w;
        }
        __syncthreads();
    }

#pragma unroll
    for (int i = 0; i < 4; i++) {
        size_t fo = ((size_t)m * N_ + rowbase + row4 + i) * HD_ + colbase + col4;
        ushort4 f4;
        f4.x = f2bf(acc[i][0]); f4.y = f2bf(acc[i][1]);
        f4.z = f2bf(acc[i][2]); f4.w = f2bf(acc[i][3]);
        *(ushort4*)&feat[fo] = f4;
    }

    const int head = (colbase + col4) >> 6;
    const int d0   = (colbase + col4) & 63;
    const float* alp = al + ((m * H_ + head) * D_ + d0);
    const float* arp = ar + ((m * H_ + head) * D_ + d0);
    float4 av = *(const float4*)alp;
    float4 rv = *(const float4*)arp;
    float vl[4], vr[4];
#pragma unroll
    for (int i = 0; i < 4; i++) {
        vl[i] = acc[i][0] * av.x + acc[i][1] * av.y + acc[i][2] * av.z + acc[i][3] * av.w;
        vr[i] = acc[i][0] * rv.x + acc[i][1] * rv.y + acc[i][2] * rv.z + acc[i][3] * rv.w;
    }
    for (int off = 8; off; off >>= 1) {
#pragma unroll
        for (int i = 0; i < 4; i++) {
            vl[i] += __shfl_down(vl[i], off, 16);
            vr[i] += __shfl_down(vr[i], off, 16);
        }
    }
    if ((tx & 15) == 0) {
#pragma unroll
        for (int i = 0; i < 4; i++) {
            int o = (m * N_ + rowbase + row4 + i) * H_ + head;
            el[o] = vl[i];
            er[o] = vr[i];
        }
    }
}

// K1b: W1T[n][k] = bf16(W1[k][n]) — tiny one-off transpose for MFMA B-frags
__global__ __launch_bounds__(256) void prep_w1t(const float* __restrict__ W1,
                                                ushort* __restrict__ W1T) {
    int idx = blockIdx.x * 256 + threadIdx.x;      // 0..32767
    int n = idx >> 8, k = idx & 255;
    W1T[idx] = f2bf(W1[(size_t)k * HID_ + n]);
}

// K2: in-degree histogram over (m, dst)
__global__ __launch_bounds__(256) void hist_kernel(const int* __restrict__ dst,
                                                   int* __restrict__ cnt) {
    int i = blockIdx.x * 256 + threadIdx.x;
    if (i >= ME_) return;
    int m = i / E_;
    atomicAdd(&cnt[m * N_ + dst[i]], 1);
}

// K3a: per-block scan
__global__ __launch_bounds__(256) void scan_phase1(const int* __restrict__ cnt,
                                                   int* __restrict__ rowstart,
                                                   int* __restrict__ blocksum) {
    __shared__ int lds[256];
    const int t = threadIdx.x;
    const int i = blockIdx.x * 256 + t;
    int v = (i < MN_) ? cnt[i] : 0;
    lds[t] = v;
    for (int s = 1; s < 256; s <<= 1) {
        __syncthreads();
        int tmp = (t >= s) ? lds[t - s] : 0;
        __syncthreads();
        lds[t] += tmp;
    }
    __syncthreads();
    if (i < MN_) rowstart[i] = lds[t] - v;
    if (t == 255) blocksum[blockIdx.x] = lds[255];
}

// K3b: scan block sums
__global__ __launch_bounds__(256) void scan_phase2(const int* __restrict__ blocksum,
                                                   int* __restrict__ blockoff) {
    __shared__ int lds[256];
    const int t = threadIdx.x;
    int v = (t < NB_) ? blocksum[t] : 0;
    lds[t] = v;
    for (int s = 1; s < 256; s <<= 1) {
        __syncthreads();
        int tmp = (t >= s) ? lds[t - s] : 0;
        __syncthreads();
        lds[t] += tmp;
    }
    __syncthreads();
    if (t < NB_) blockoff[t] = lds[t] - v;
}

// K3c: add block offsets
__global__ __launch_bounds__(256) void scan_phase3(int* __restrict__ rowstart,
                                                   const int* __restrict__ blockoff,
                                                   int* __restrict__ cursor) {
    const int i = blockIdx.x * 256 + threadIdx.x;
    if (i < MN_) {
        int v = rowstart[i] + blockoff[i >> 8];
        rowstart[i] = v;
        cursor[i]   = v;
    }
    if (i == 0) rowstart[MN_] = ME_;
}

// K4: scatter edge src ids into CSR order
__global__ __launch_bounds__(256) void scatter_kernel(const int* __restrict__ src,
                                                      const int* __restrict__ dst,
                                                      int* __restrict__ cursor,
                                                      int* __restrict__ esrc) {
    int i = blockIdx.x * 256 + threadIdx.x;
    if (i >= ME_) return;
    int m = i / E_;
    int pos = atomicAdd(&cursor[m * N_ + dst[i]], 1);
    esrc[pos] = src[i];
}

// K5: wave per (m, dst): single-pass softmax-weighted aggregation, 4-wide MLP unroll
__global__ __launch_bounds__(256) void aggregate_csr(
    const int* __restrict__ rowstart, const int* __restrict__ esrc,
    const float* __restrict__ el, const float* __restrict__ er,
    const ushort* __restrict__ feat, const float* __restrict__ bias,
    float* __restrict__ z) {
    const int g = blockIdx.x * 4 + (threadIdx.x >> 6);   // m*N + n
    const int lane = threadIdx.x & 63;
    const int m = g / N_;
    const int head = lane >> 4;
    const int beg = rowstart[g], end = rowstart[g + 1];
    const float erv = er[(size_t)g * H_ + head];
    const int mN = m * N_;
    const ushort* fm = feat + (size_t)mN * HD_;
    float a0 = 0.f, a1 = 0.f, a2 = 0.f, a3 = 0.f, den = 0.f;

    int j = beg;
    for (; j + 4 <= end; j += 4) {
        int s0 = esrc[j], s1 = esrc[j + 1], s2 = esrc[j + 2], s3 = esrc[j + 3];
        float x0 = el[(size_t)(mN + s0) * H_ + head] + erv;
        float x1 = el[(size_t)(mN + s1) * H_ + head] + erv;
        float x2 = el[(size_t)(mN + s2) * H_ + head] + erv;
        float x3 = el[(size_t)(mN + s3) * H_ + head] + erv;
        ushort4 f0 = *(const ushort4*)&fm[(size_t)s0 * HD_ + 4 * lane];
        ushort4 f1 = *(const ushort4*)&fm[(size_t)s1 * HD_ + 4 * lane];
        ushort4 f2 = *(const ushort4*)&fm[(size_t)s2 * HD_ + 4 * lane];
        ushort4 f3 = *(const ushort4*)&fm[(size_t)s3 * HD_ + 4 * lane];
        x0 = x0 > 0.f ? x0 : NEG_SLOPE * x0;
        x1 = x1 > 0.f ? x1 : NEG_SLOPE * x1;
        x2 = x2 > 0.f ? x2 : NEG_SLOPE * x2;
        x3 = x3 > 0.f ? x3 : NEG_SLOPE * x3;
        float e0 = __expf(x0), e1 = __expf(x1), e2 = __expf(x2), e3 = __expf(x3);
        a0 += e0 * bf2f(f0.x) + e1 * bf2f(f1.x) + e2 * bf2f(f2.x) + e3 * bf2f(f3.x);
        a1 += e0 * bf2f(f0.y) + e1 * bf2f(f1.y) + e2 * bf2f(f2.y) + e3 * bf2f(f3.y);
        a2 += e0 * bf2f(f0.z) + e1 * bf2f(f1.z) + e2 * bf2f(f2.z) + e3 * bf2f(f3.z);
        a3 += e0 * bf2f(f0.w) + e1 * bf2f(f1.w) + e2 * bf2f(f2.w) + e3 * bf2f(f3.w);
        den += e0 + e1 + e2 + e3;
    }
    for (; j < end; j++) {
        int s = esrc[j];
        float x = el[(size_t)(mN + s) * H_ + head] + erv;
        x = x > 0.f ? x : NEG_SLOPE * x;
        float ee = __expf(x);
        ushort4 f4 = *(const ushort4*)&fm[(size_t)s * HD_ + 4 * lane];
        a0 += ee * bf2f(f4.x);
        a1 += ee * bf2f(f4.y);
        a2 += ee * bf2f(f4.z);
        a3 += ee * bf2f(f4.w);
        den += ee;
    }
    float inv = 1.f / fmaxf(den, 1e-9f);
    float4 b4 = *(const float4*)&bias[m * HD_ + 4 * lane];
    float4 o;
    o.x = a0 * inv + b4.x;
    o.y = a1 * inv + b4.y;
    o.z = a2 * inv + b4.z;
    o.w = a3 * inv + b4.w;
    *(float4*)&z[(size_t)g * HD_ + 4 * lane] = o;
}

// K6: MFMA semantic attention. Block = 128 threads = 2 waves; wave covers
// 16 rows x 128 cols of tanh(z@W1+b1), dotted with W2, reduced to one
// atomicAdd per block into wsum[m]. A-frags: z fp32 -> bf16 on the fly
// (k = quad*8+j is 8 contiguous floats). B-frags: 16B loads from bf16 W1T.
// C/D layout (m89-verified): col = lane&15, row = (lane>>4)*4 + reg — we only
// need the full sum, so layout collapses into a 64-lane reduction.
__global__ __launch_bounds__(128) void semantic_w(
    const float* __restrict__ z, const ushort* __restrict__ W1T,
    const float* __restrict__ b1, const float* __restrict__ W2,
    float* __restrict__ wsum) {
    const int tx   = threadIdx.x;
    const int wv   = tx >> 6;                       // 0..1
    const int lane = tx & 63;
    const int lrow = lane & 15;
    const int kq   = lane >> 4;                     // quad 0..3
    const int rowbase = blockIdx.x * 32 + wv * 16;  // 32 rows per block
    const int m = (blockIdx.x * 32) / N_;           // uniform per block (32 | 20000)

    f32x4 acc[8];
#pragma unroll
    for (int g = 0; g < 8; g++) acc[g] = {0.f, 0.f, 0.f, 0.f};

    const float* zrow = z + (size_t)(rowbase + lrow) * HD_ + kq * 8;
    for (int k0 = 0; k0 < HD_; k0 += 32) {
        float4 f0 = *(const float4*)&zrow[k0];
        float4 f1 = *(const float4*)&zrow[k0 + 4];
        short8 a;
        a[0] = (short)f2bf(f0.x); a[1] = (short)f2bf(f0.y);
        a[2] = (short)f2bf(f0.z); a[3] = (short)f2bf(f0.w);
        a[4] = (short)f2bf(f1.x); a[5] = (short)f2bf(f1.y);
        a[6] = (short)f2bf(f1.z); a[7] = (short)f2bf(f1.w);
#pragma unroll
        for (int g = 0; g < 8; g++) {
            short8 b = *(const short8*)&W1T[(size_t)(16 * g + lrow) * HD_ + k0 + kq * 8];
            acc[g] = __builtin_amdgcn_mfma_f32_16x16x32_bf16(a, b, acc[g], 0, 0, 0);
        }
    }

    float local = 0.f;
#pragma unroll
    for (int g = 0; g < 8; g++) {
        int col = 16 * g + lrow;
        float bb = b1[col], w2 = W2[col];
        local += tanhf(acc[g][0] + bb) * w2;
        local += tanhf(acc[g][1] + bb) * w2;
        local += tanhf(acc[g][2] + bb) * w2;
        local += tanhf(acc[g][3] + bb) * w2;
    }
    for (int off = 32; off; off >>= 1) local += __shfl_down(local, off);
    __shared__ float red[2];
    if (lane == 0) red[wv] = local;
    __syncthreads();
    if (tx == 0) atomicAdd(&wsum[m], red[0] + red[1]);
}

// K7: out[n][c] = sum_m beta[m] * z[m][n][c]; beta computed inline from wsum.
__global__ __launch_bounds__(256) void final_out(
    const float* __restrict__ z, const float* __restrict__ wsum,
    float* __restrict__ out) {
    int idx = blockIdx.x * 256 + threadIdx.x;       // float4 index over [N*HD/4]
    if (idx >= N_ * HD_ / 4) return;
    float w0 = wsum[0], w1 = wsum[1], w2 = wsum[2];
    float mx = fmaxf(w0, fmaxf(w1, w2));
    float e0 = __expf((w0 - mx) / (float)N_);
    float e1 = __expf((w1 - mx) / (float)N_);
    float e2 = __expf((w2 - mx) / (float)N_);
    float sinv = 1.f / (e0 + e1 + e2);
    float b0 = e0 * sinv, b1 = e1 * sinv, b2 = e2 * sinv;
    float4 z0 = *(const float4*)&z[(size_t)idx * 4];
    float4 z1 = *(const float4*)&z[(size_t)N_ * HD_ + (size_t)idx * 4];
    float4 z2 = *(const float4*)&z[(size_t)2 * N_ * HD_ + (size_t)idx * 4];
    float4 o;
    o.x = b0 * z0.x + b1 * z1.x + b2 * z2.x;
    o.y = b0 * z0.y + b1 * z1.y + b2 * z2.y;
    o.z = b0 * z0.z + b1 * z1.z + b2 * z2.z;
    o.w = b0 * z0.w + b1 * z1.w + b2 * z2.w;
    *(float4*)&out[(size_t)idx * 4] = o;
}

extern "C" void kernel_launch(void* const* d_in, const int* in_sizes, int n_in,
                              void* d_out, int out_size, void* d_ws, size_t ws_size,
                              hipStream_t stream) {
    const float* h    = (const float*)d_in[0];
    const int*   src  = (const int*)d_in[1];
    const int*   dst  = (const int*)d_in[2];
    const float* W    = (const float*)d_in[3];
    const float* al   = (const float*)d_in[4];
    const float* ar   = (const float*)d_in[5];
    const float* bias = (const float*)d_in[6];
    const float* W1   = (const float*)d_in[7];
    const float* b1   = (const float*)d_in[8];
    const float* W2   = (const float*)d_in[9];

    char* ws = (char*)d_ws;
    ushort* feat     = (ushort*)(ws + FEAT_OFF);
    float*  z        = (float*)(ws + Z_OFF);
    float*  el       = (float*)(ws + EL_OFF);
    float*  er       = (float*)(ws + ER_OFF);
    int*    esrc     = (int*)(ws + ESRC_OFF);
    int*    rowstart = (int*)(ws + ROW_OFF);
    int*    cursor   = (int*)(ws + CUR_OFF);
    int*    cnt      = (int*)(ws + CNT_OFF);
    float*  wsum     = (float*)(ws + WSUM_OFF);
    int*    blocksum = (int*)(ws + BS_OFF);
    int*    blockoff = (int*)(ws + BO_OFF);
    ushort* w1t      = (ushort*)(ws + W1T_OFF);

    // zero cnt + wsum (contiguous)
    hipMemsetAsync(ws + CNT_OFF, 0, 240000 + 64, stream);

    feat_gemm<<<dim3(N_ / 32, 2 * M_), 256, 0, stream>>>(h, W, al, ar, feat, el, er);
    prep_w1t<<<HID_ * HD_ / 256, 256, 0, stream>>>(W1, w1t);
    hist_kernel<<<(ME_ + 255) / 256, 256, 0, stream>>>(dst, cnt);
    scan_phase1<<<NB_, 256, 0, stream>>>(cnt, rowstart, blocksum);
    scan_phase2<<<1, 256, 0, stream>>>(blocksum, blockoff);
    scan_phase3<<<NB_, 256, 0, stream>>>(rowstart, blockoff, cursor);
    scatter_kernel<<<(ME_ + 255) / 256, 256, 0, stream>>>(src, dst, cursor, esrc);
    aggregate_csr<<<MN_ / 4, 256, 0, stream>>>(rowstart, esrc, el, er, feat, bias, z);
    semantic_w<<<MN_ / 32, 128, 0, stream>>>(z, w1t, b1, W2, wsum);
    final_out<<<N_ * HD_ / 4 / 256, 256, 0, stream>>>(z, wsum, (float*)d_out);
}

// Round 8
// 359.574 us; speedup vs baseline: 12.4966x; 1.0543x over previous
//
#include <hip/hip_runtime.h>
#include <hip/hip_bf16.h>

// Problem constants
constexpr int N_   = 20000;
constexpr int E_   = 320000;
constexpr int M_   = 3;
constexpr int KIN  = 128;   // in_size
constexpr int H_   = 4;     // heads
constexpr int D_   = 64;    // per-head dim
constexpr int HD_  = 256;   // H*D
constexpr int HID_ = 128;   // semantic hidden
constexpr int MN_  = M_ * N_;   // 60000 segments
constexpr int ME_  = M_ * E_;   // 960000 edges
constexpr int NB_  = (MN_ + 255) / 256;  // 235 scan blocks
#define NEG_SLOPE 0.2f

// Workspace layout (bytes) — ~98.7 MB
constexpr size_t FEAT_OFF = 0;           // ushort[M*N*HD]  = 30,720,000 (internal bf16 feat)
constexpr size_t Z_OFF    = 30720000;    // float [M*N*HD]  = 61,440,000
constexpr size_t EL_OFF   = 92160000;    // float [M*N*H]   =    960,000
constexpr size_t ER_OFF   = 93120000;    // float [M*N*H]   =    960,000
constexpr size_t ESRC_OFF = 94080000;    // int   [M*E]     =  3,840,000 (CSR-ordered src ids)
constexpr size_t ROW_OFF  = 97920000;    // int   [MN+1]    =    240,064 (padded)
constexpr size_t CUR_OFF  = 98160064;    // int   [MN]      =    240,000 (scatter cursors)
constexpr size_t CNT_OFF  = 98400064;    // int   [MN]      =    240,000 (histogram)  } memset
constexpr size_t WSUM_OFF = 98640064;    // float [16]                               } together
constexpr size_t BS_OFF   = 98640128;    // int   [256]  per-block sums
constexpr size_t BO_OFF   = 98641152;    // int   [256]  per-block offsets
constexpr size_t W1T_OFF  = 98642176;    // ushort[HID*HD] = 65,536 (bf16 W1 transposed)
// hb / wt overlap the z region: z is written only by aggregate_csr, which runs
// strictly after feat_gemm_mfma (the only consumer of hb/wt) in stream order.
constexpr size_t HB_OFF   = Z_OFF;               // ushort[N*KIN] = 5,120,000 (bf16 h)
constexpr size_t WT_OFF   = Z_OFF + 5120000;     // ushort[M*HD*KIN] = 196,608 (bf16 W, col-sigma-permuted, transposed)

typedef __attribute__((ext_vector_type(8))) short short8;   // 8 bf16 (4 VGPRs)
typedef __attribute__((ext_vector_type(4))) float f32x4;    // MFMA accumulator

__device__ __forceinline__ float bf2f(ushort u) {
    union { unsigned int i; float f; } v; v.i = ((unsigned int)u) << 16; return v.f;
}
__device__ __forceinline__ ushort f2bf(float f) {
    union { float f; unsigned int i; } v; v.f = f;
    unsigned int i = v.i;
    unsigned int r = (i + 0x7fffu + ((i >> 16) & 1u)) >> 16;   // RNE
    return (ushort)r;
}

// K0: pack h -> bf16 hb; build WT[m][n][k] = bf16(W[m][k][sigma(n)]) with
// sigma(n) = (n&15)*16 + (n>>4) (self-inverse), and W1T[n][k] = bf16(W1[k][n]).
// The sigma permutation makes the MFMA C-fragment stores land at CONTIGUOUS
// standard feat columns (thread's 16 values -> cols l15*16..l15*16+15).
__global__ __launch_bounds__(256) void prep_pack(
    const float* __restrict__ h, const float* __restrict__ W,
    const float* __restrict__ W1, ushort* __restrict__ hb,
    ushort* __restrict__ wt, ushort* __restrict__ w1t) {
    const int b = blockIdx.x, t = threadIdx.x;
    if (b < 2500) {                                 // hb: 2500*1024 = N*KIN
        int i4 = b * 1024 + t * 4;
        float4 v = *(const float4*)&h[i4];
        ushort4 o; o.x = f2bf(v.x); o.y = f2bf(v.y); o.z = f2bf(v.z); o.w = f2bf(v.w);
        *(ushort4*)&hb[i4] = o;
    } else {
        int f = (b - 2500) * 1024 + t * 4;          // 0..131071
        if (f < 3 * HD_ * KIN) {                    // wt: 98304 elements
            int m = f >> 15, r = f & 32767, n = r >> 7, k0 = r & 127;
            int c = ((n & 15) << 4) | (n >> 4);     // sigma(n)
            const float* src = W + (size_t)m * KIN * HD_ + c;
            ushort4 o;
            o.x = f2bf(src[(size_t)(k0 + 0) * HD_]);
            o.y = f2bf(src[(size_t)(k0 + 1) * HD_]);
            o.z = f2bf(src[(size_t)(k0 + 2) * HD_]);
            o.w = f2bf(src[(size_t)(k0 + 3) * HD_]);
            *(ushort4*)&wt[f] = o;
        } else {                                    // w1t: 32768 elements
            int f2 = f - 3 * HD_ * KIN;
            int n = f2 >> 8, k0 = f2 & 255;
            const float* src = W1 + n;
            ushort4 o;
            o.x = f2bf(src[(size_t)(k0 + 0) * HID_]);
            o.y = f2bf(src[(size_t)(k0 + 1) * HID_]);
            o.z = f2bf(src[(size_t)(k0 + 2) * HID_]);
            o.w = f2bf(src[(size_t)(k0 + 3) * HID_]);
            *(ushort4*)&w1t[f2] = o;
        }
    }
}

// K1: MFMA feat = h @ W[m] (bf16) + fused el/er epilogue.
// Block = 128 = 2 waves; wave -> 16 rows x 256 cols; grid (625, 3).
// acc[g][reg] = C[row=kq*4+reg][n=16g+l15] = feat[row][c = sigma(n) = l15*16+g].
// Per (reg): thread's 16 values are feat cols l15*16..l15*16+15 -> contiguous.
// head(c) = c>>6 = l15>>2 (uniform per thread); al idx c&63 = (l15&3)*16+g.
__global__ __launch_bounds__(128) void feat_gemm_mfma(
    const ushort* __restrict__ hb, const ushort* __restrict__ wt,
    const float* __restrict__ al, const float* __restrict__ ar,
    ushort* __restrict__ feat, float* __restrict__ el, float* __restrict__ er) {
    const int wv   = threadIdx.x >> 6;
    const int lane = threadIdx.x & 63;
    const int l15  = lane & 15, kq = lane >> 4;
    const int m    = blockIdx.y;
    const int rowbase = blockIdx.x * 32 + wv * 16;

    f32x4 acc[16];
#pragma unroll
    for (int g = 0; g < 16; g++) acc[g] = {0.f, 0.f, 0.f, 0.f};

    const ushort* ha = hb + (size_t)(rowbase + l15) * KIN + kq * 8;
    const ushort* wb = wt + ((size_t)m * HD_ + l15) * KIN + kq * 8;
    for (int kb = 0; kb < KIN; kb += 32) {
        short8 a = *(const short8*)&ha[kb];
#pragma unroll
        for (int g = 0; g < 16; g++) {
            short8 b = *(const short8*)&wb[(size_t)(16 * g) * KIN + kb];
            acc[g] = __builtin_amdgcn_mfma_f32_16x16x32_bf16(a, b, acc[g], 0, 0, 0);
        }
    }

    // feat store: 4 rows x 16 contiguous cols (2x16B per row)
#pragma unroll
    for (int reg = 0; reg < 4; reg++) {
        int row = rowbase + kq * 4 + reg;
        short8 v0, v1;
#pragma unroll
        for (int g = 0; g < 8; g++) {
            v0[g] = (short)f2bf(acc[g][reg]);
            v1[g] = (short)f2bf(acc[g + 8][reg]);
        }
        size_t fo = ((size_t)m * N_ + row) * HD_ + l15 * 16;
        *(short8*)&feat[fo]     = v0;
        *(short8*)&feat[fo + 8] = v1;
    }

    // el/er epilogue
    const int head = l15 >> 2;
    const float* alp = al + ((size_t)(m * H_ + head)) * D_ + ((l15 & 3) << 4);
    const float* arp = ar + ((size_t)(m * H_ + head)) * D_ + ((l15 & 3) << 4);
    float4 av0 = *(const float4*)&alp[0],  av1 = *(const float4*)&alp[4];
    float4 av2 = *(const float4*)&alp[8],  av3 = *(const float4*)&alp[12];
    float4 rv0 = *(const float4*)&arp[0],  rv1 = *(const float4*)&arp[4];
    float4 rv2 = *(const float4*)&arp[8],  rv3 = *(const float4*)&arp[12];
    float pl[4], pr[4];
#pragma unroll
    for (int reg = 0; reg < 4; reg++) {
        pl[reg] = acc[0][reg]*av0.x + acc[1][reg]*av0.y + acc[2][reg]*av0.z + acc[3][reg]*av0.w
                + acc[4][reg]*av1.x + acc[5][reg]*av1.y + acc[6][reg]*av1.z + acc[7][reg]*av1.w
                + acc[8][reg]*av2.x + acc[9][reg]*av2.y + acc[10][reg]*av2.z + acc[11][reg]*av2.w
                + acc[12][reg]*av3.x + acc[13][reg]*av3.y + acc[14][reg]*av3.z + acc[15][reg]*av3.w;
        pr[reg] = acc[0][reg]*rv0.x + acc[1][reg]*rv0.y + acc[2][reg]*rv0.z + acc[3][reg]*rv0.w
                + acc[4][reg]*rv1.x + acc[5][reg]*rv1.y + acc[6][reg]*rv1.z + acc[7][reg]*rv1.w
                + acc[8][reg]*rv2.x + acc[9][reg]*rv2.y + acc[10][reg]*rv2.z + acc[11][reg]*rv2.w
                + acc[12][reg]*rv3.x + acc[13][reg]*rv3.y + acc[14][reg]*rv3.z + acc[15][reg]*rv3.w;
    }
    // reduce over the 4 lanes sharing (kq, head): contiguous lane groups of 4
#pragma unroll
    for (int off = 2; off; off >>= 1) {
#pragma unroll
        for (int reg = 0; reg < 4; reg++) {
            pl[reg] += __shfl_down(pl[reg], off, 4);
            pr[reg] += __shfl_down(pr[reg], off, 4);
        }
    }
    if ((l15 & 3) == 0) {
#pragma unroll
        for (int reg = 0; reg < 4; reg++) {
            int row = rowbase + kq * 4 + reg;
            int o = (m * N_ + row) * H_ + head;
            el[o] = pl[reg];
            er[o] = pr[reg];
        }
    }
}

// K2: in-degree histogram over (m, dst)
__global__ __launch_bounds__(256) void hist_kernel(const int* __restrict__ dst,
                                                   int* __restrict__ cnt) {
    int i = blockIdx.x * 256 + threadIdx.x;
    if (i >= ME_) return;
    int m = i / E_;
    atomicAdd(&cnt[m * N_ + dst[i]], 1);
}

// K3a: per-block scan
__global__ __launch_bounds__(256) void scan_phase1(const int* __restrict__ cnt,
                                                   int* __restrict__ rowstart,
                                                   int* __restrict__ blocksum) {
    __shared__ int lds[256];
    const int t = threadIdx.x;
    const int i = blockIdx.x * 256 + t;
    int v = (i < MN_) ? cnt[i] : 0;
    lds[t] = v;
    for (int s = 1; s < 256; s <<= 1) {
        __syncthreads();
        int tmp = (t >= s) ? lds[t - s] : 0;
        __syncthreads();
        lds[t] += tmp;
    }
    __syncthreads();
    if (i < MN_) rowstart[i] = lds[t] - v;
    if (t == 255) blocksum[blockIdx.x] = lds[255];
}

// K3b: scan block sums
__global__ __launch_bounds__(256) void scan_phase2(const int* __restrict__ blocksum,
                                                   int* __restrict__ blockoff) {
    __shared__ int lds[256];
    const int t = threadIdx.x;
    int v = (t < NB_) ? blocksum[t] : 0;
    lds[t] = v;
    for (int s = 1; s < 256; s <<= 1) {
        __syncthreads();
        int tmp = (t >= s) ? lds[t - s] : 0;
        __syncthreads();
        lds[t] += tmp;
    }
    __syncthreads();
    if (t < NB_) blockoff[t] = lds[t] - v;
}

// K3c: add block offsets
__global__ __launch_bounds__(256) void scan_phase3(int* __restrict__ rowstart,
                                                   const int* __restrict__ blockoff,
                                                   int* __restrict__ cursor) {
    const int i = blockIdx.x * 256 + threadIdx.x;
    if (i < MN_) {
        int v = rowstart[i] + blockoff[i >> 8];
        rowstart[i] = v;
        cursor[i]   = v;
    }
    if (i == 0) rowstart[MN_] = ME_;
}

// K4: scatter edge src ids into CSR order
__global__ __launch_bounds__(256) void scatter_kernel(const int* __restrict__ src,
                                                      const int* __restrict__ dst,
                                                      int* __restrict__ cursor,
                                                      int* __restrict__ esrc) {
    int i = blockIdx.x * 256 + threadIdx.x;
    if (i >= ME_) return;
    int m = i / E_;
    int pos = atomicAdd(&cursor[m * N_ + dst[i]], 1);
    esrc[pos] = src[i];
}

// K5: wave per (m, dst): single-pass softmax-weighted aggregation, 4-wide MLP unroll
__global__ __launch_bounds__(256) void aggregate_csr(
    const int* __restrict__ rowstart, const int* __restrict__ esrc,
    const float* __restrict__ el, const float* __restrict__ er,
    const ushort* __restrict__ feat, const float* __restrict__ bias,
    float* __restrict__ z) {
    const int g = blockIdx.x * 4 + (threadIdx.x >> 6);   // m*N + n
    const int lane = threadIdx.x & 63;
    const int m = g / N_;
    const int head = lane >> 4;
    const int beg = rowstart[g], end = rowstart[g + 1];
    const float erv = er[(size_t)g * H_ + head];
    const int mN = m * N_;
    const ushort* fm = feat + (size_t)mN * HD_;
    float a0 = 0.f, a1 = 0.f, a2 = 0.f, a3 = 0.f, den = 0.f;

    int j = beg;
    for (; j + 4 <= end; j += 4) {
        int s0 = esrc[j], s1 = esrc[j + 1], s2 = esrc[j + 2], s3 = esrc[j + 3];
        float x0 = el[(size_t)(mN + s0) * H_ + head] + erv;
        float x1 = el[(size_t)(mN + s1) * H_ + head] + erv;
        float x2 = el[(size_t)(mN + s2) * H_ + head] + erv;
        float x3 = el[(size_t)(mN + s3) * H_ + head] + erv;
        ushort4 f0 = *(const ushort4*)&fm[(size_t)s0 * HD_ + 4 * lane];
        ushort4 f1 = *(const ushort4*)&fm[(size_t)s1 * HD_ + 4 * lane];
        ushort4 f2 = *(const ushort4*)&fm[(size_t)s2 * HD_ + 4 * lane];
        ushort4 f3 = *(const ushort4*)&fm[(size_t)s3 * HD_ + 4 * lane];
        x0 = x0 > 0.f ? x0 : NEG_SLOPE * x0;
        x1 = x1 > 0.f ? x1 : NEG_SLOPE * x1;
        x2 = x2 > 0.f ? x2 : NEG_SLOPE * x2;
        x3 = x3 > 0.f ? x3 : NEG_SLOPE * x3;
        float e0 = __expf(x0), e1 = __expf(x1), e2 = __expf(x2), e3 = __expf(x3);
        a0 += e0 * bf2f(f0.x) + e1 * bf2f(f1.x) + e2 * bf2f(f2.x) + e3 * bf2f(f3.x);
        a1 += e0 * bf2f(f0.y) + e1 * bf2f(f1.y) + e2 * bf2f(f2.y) + e3 * bf2f(f3.y);
        a2 += e0 * bf2f(f0.z) + e1 * bf2f(f1.z) + e2 * bf2f(f2.z) + e3 * bf2f(f3.z);
        a3 += e0 * bf2f(f0.w) + e1 * bf2f(f1.w) + e2 * bf2f(f2.w) + e3 * bf2f(f3.w);
        den += e0 + e1 + e2 + e3;
    }
    for (; j < end; j++) {
        int s = esrc[j];
        float x = el[(size_t)(mN + s) * H_ + head] + erv;
        x = x > 0.f ? x : NEG_SLOPE * x;
        float ee = __expf(x);
        ushort4 f4 = *(const ushort4*)&fm[(size_t)s * HD_ + 4 * lane];
        a0 += ee * bf2f(f4.x);
        a1 += ee * bf2f(f4.y);
        a2 += ee * bf2f(f4.z);
        a3 += ee * bf2f(f4.w);
        den += ee;
    }
    float inv = 1.f / fmaxf(den, 1e-9f);
    float4 b4 = *(const float4*)&bias[m * HD_ + 4 * lane];
    float4 o;
    o.x = a0 * inv + b4.x;
    o.y = a1 * inv + b4.y;
    o.z = a2 * inv + b4.z;
    o.w = a3 * inv + b4.w;
    *(float4*)&z[(size_t)g * HD_ + 4 * lane] = o;
}

// K6: MFMA semantic attention (unchanged from round 7).
__global__ __launch_bounds__(128) void semantic_w(
    const float* __restrict__ z, const ushort* __restrict__ W1T,
    const float* __restrict__ b1, const float* __restrict__ W2,
    float* __restrict__ wsum) {
    const int tx   = threadIdx.x;
    const int wv   = tx >> 6;
    const int lane = tx & 63;
    const int lrow = lane & 15;
    const int kq   = lane >> 4;
    const int rowbase = blockIdx.x * 32 + wv * 16;
    const int m = (blockIdx.x * 32) / N_;

    f32x4 acc[8];
#pragma unroll
    for (int g = 0; g < 8; g++) acc[g] = {0.f, 0.f, 0.f, 0.f};

    const float* zrow = z + (size_t)(rowbase + lrow) * HD_ + kq * 8;
    for (int k0 = 0; k0 < HD_; k0 += 32) {
        float4 f0 = *(const float4*)&zrow[k0];
        float4 f1 = *(const float4*)&zrow[k0 + 4];
        short8 a;
        a[0] = (short)f2bf(f0.x); a[1] = (short)f2bf(f0.y);
        a[2] = (short)f2bf(f0.z); a[3] = (short)f2bf(f0.w);
        a[4] = (short)f2bf(f1.x); a[5] = (short)f2bf(f1.y);
        a[6] = (short)f2bf(f1.z); a[7] = (short)f2bf(f1.w);
#pragma unroll
        for (int g = 0; g < 8; g++) {
            short8 b = *(const short8*)&W1T[(size_t)(16 * g + lrow) * HD_ + k0 + kq * 8];
            acc[g] = __builtin_amdgcn_mfma_f32_16x16x32_bf16(a, b, acc[g], 0, 0, 0);
        }
    }

    float local = 0.f;
#pragma unroll
    for (int g = 0; g < 8; g++) {
        int col = 16 * g + lrow;
        float bb = b1[col], w2 = W2[col];
        local += tanhf(acc[g][0] + bb) * w2;
        local += tanhf(acc[g][1] + bb) * w2;
        local += tanhf(acc[g][2] + bb) * w2;
        local += tanhf(acc[g][3] + bb) * w2;
    }
    for (int off = 32; off; off >>= 1) local += __shfl_down(local, off);
    __shared__ float red[2];
    if (lane == 0) red[wv] = local;
    __syncthreads();
    if (tx == 0) atomicAdd(&wsum[m], red[0] + red[1]);
}

// K7: out[n][c] = sum_m beta[m] * z[m][n][c]; beta computed inline from wsum.
__global__ __launch_bounds__(256) void final_out(
    const float* __restrict__ z, const float* __restrict__ wsum,
    float* __restrict__ out) {
    int idx = blockIdx.x * 256 + threadIdx.x;
    if (idx >= N_ * HD_ / 4) return;
    float w0 = wsum[0], w1 = wsum[1], w2 = wsum[2];
    float mx = fmaxf(w0, fmaxf(w1, w2));
    float e0 = __expf((w0 - mx) / (float)N_);
    float e1 = __expf((w1 - mx) / (float)N_);
    float e2 = __expf((w2 - mx) / (float)N_);
    float sinv = 1.f / (e0 + e1 + e2);
    float b0 = e0 * sinv, b1 = e1 * sinv, b2 = e2 * sinv;
    float4 z0 = *(const float4*)&z[(size_t)idx * 4];
    float4 z1 = *(const float4*)&z[(size_t)N_ * HD_ + (size_t)idx * 4];
    float4 z2 = *(const float4*)&z[(size_t)2 * N_ * HD_ + (size_t)idx * 4];
    float4 o;
    o.x = b0 * z0.x + b1 * z1.x + b2 * z2.x;
    o.y = b0 * z0.y + b1 * z1.y + b2 * z2.y;
    o.z = b0 * z0.z + b1 * z1.z + b2 * z2.z;
    o.w = b0 * z0.w + b1 * z1.w + b2 * z2.w;
    *(float4*)&out[(size_t)idx * 4] = o;
}

extern "C" void kernel_launch(void* const* d_in, const int* in_sizes, int n_in,
                              void* d_out, int out_size, void* d_ws, size_t ws_size,
                              hipStream_t stream) {
    const float* h    = (const float*)d_in[0];
    const int*   src  = (const int*)d_in[1];
    const int*   dst  = (const int*)d_in[2];
    const float* W    = (const float*)d_in[3];
    const float* al   = (const float*)d_in[4];
    const float* ar   = (const float*)d_in[5];
    const float* bias = (const float*)d_in[6];
    const float* W1   = (const float*)d_in[7];
    const float* b1   = (const float*)d_in[8];
    const float* W2   = (const float*)d_in[9];

    char* ws = (char*)d_ws;
    ushort* feat     = (ushort*)(ws + FEAT_OFF);
    float*  z        = (float*)(ws + Z_OFF);
    float*  el       = (float*)(ws + EL_OFF);
    float*  er       = (float*)(ws + ER_OFF);
    int*    esrc     = (int*)(ws + ESRC_OFF);
    int*    rowstart = (int*)(ws + ROW_OFF);
    int*    cursor   = (int*)(ws + CUR_OFF);
    int*    cnt      = (int*)(ws + CNT_OFF);
    float*  wsum     = (float*)(ws + WSUM_OFF);
    int*    blocksum = (int*)(ws + BS_OFF);
    int*    blockoff = (int*)(ws + BO_OFF);
    ushort* w1t      = (ushort*)(ws + W1T_OFF);
    ushort* hb       = (ushort*)(ws + HB_OFF);
    ushort* wt       = (ushort*)(ws + WT_OFF);

    // zero cnt + wsum (contiguous)
    hipMemsetAsync(ws + CNT_OFF, 0, 240000 + 64, stream);

    prep_pack<<<2500 + 128, 256, 0, stream>>>(h, W, W1, hb, wt, w1t);
    feat_gemm_mfma<<<dim3(N_ / 32, M_), 128, 0, stream>>>(hb, wt, al, ar, feat, el, er);
    hist_kernel<<<(ME_ + 255) / 256, 256, 0, stream>>>(dst, cnt);
    scan_phase1<<<NB_, 256, 0, stream>>>(cnt, rowstart, blocksum);
    scan_phase2<<<1, 256, 0, stream>>>(blocksum, blockoff);
    scan_phase3<<<NB_, 256, 0, stream>>>(rowstart, blockoff, cursor);
    scatter_kernel<<<(ME_ + 255) / 256, 256, 0, stream>>>(src, dst, cursor, esrc);
    aggregate_csr<<<MN_ / 4, 256, 0, stream>>>(rowstart, esrc, el, er, feat, bias, z);
    semantic_w<<<MN_ / 32, 128, 0, stream>>>(z, w1t, b1, W2, wsum);
    final_out<<<N_ * HD_ / 4 / 256, 256, 0, stream>>>(z, wsum, (float*)d_out);
}